// Round 7
// baseline (989.007 us; speedup 1.0000x reference)
//
#include <hip/hip_runtime.h>
#include <hip/hip_bf16.h>

#define B_ 16
#define N_ 4096
#define S_ 1024
#define K_ 32
#define R_ (B_*S_*K_)   // 524288 rows
#define NBLK_ (R_/64)   // 8192 row-tiles of 64

typedef unsigned short u16;
typedef __attribute__((ext_vector_type(8))) short bf16x8;
typedef __attribute__((ext_vector_type(4))) float f32x4;

__device__ __forceinline__ u16 f2bf(float f) {
    __hip_bfloat16 h = __float2bfloat16(f);
    return __builtin_bit_cast(u16, h);
}
__device__ __forceinline__ float bf2f(u16 u) {
    unsigned x = ((unsigned)u) << 16;
    return __builtin_bit_cast(float, x);
}

// fmax(v, dpp_move<CTRL>(v)) on f64; identity-preserving (old=own, bound_ctrl=0).
template <int CTRL>
__device__ __forceinline__ double dpp_max_f64(double v) {
    unsigned long long b = (unsigned long long)__double_as_longlong(v);
    int lo = (int)(unsigned)b;
    int hi = (int)(unsigned)(b >> 32);
    int olo = __builtin_amdgcn_update_dpp(lo, lo, CTRL, 0xF, 0xF, false);
    int ohi = __builtin_amdgcn_update_dpp(hi, hi, CTRL, 0xF, 0xF, false);
    double o = __longlong_as_double(
        (long long)(((unsigned long long)(unsigned)ohi << 32) | (unsigned)olo));
    return fmax(v, o);
}

// replace low 12 mantissa bits of positive double with idx (order-preserving key)
__device__ __forceinline__ double packd(double d, int idx) {
    unsigned long long b = (unsigned long long)__double_as_longlong(d);
    b = (b & ~0xFFFull) | (unsigned)idx;
    return __longlong_as_double((long long)b);
}

// ---------------------------------------------------------------- FPS
// one block per batch, 256 threads (4 waves = 1/SIMD), 16 points/thread,
// f64 distances (+1.0 biased -> positive). dist[] stores packed keys (idx in
// low 12 mantissa bits). Per iter: 15-op fmax tree, 6-level DPP butterfly
// (lane63 = wave max), single ds_max_u64 per wave into one LDS slot
// (double-buffered, zeroed by tid0 for next iter), one barrier, broadcast b32
// read + readfirstlane -> far. Coords held f64 in LDS (no cvt on chain).
__global__ __launch_bounds__(256, 1) void fps_kernel(const float* __restrict__ xyz,
                                                     float* __restrict__ out0) {
    const int b = blockIdx.x;
    const int tid = threadIdx.x;
    const int lane = tid & 63;
    __shared__ double xs[N_], ys[N_], zs[N_];
    __shared__ unsigned long long cand[2];
    const float* xb = xyz + (size_t)b * 3 * N_;

    double x64[16], y64[16], z64[16], q64[16], dist[16];
#pragma unroll
    for (int j = 0; j < 16; ++j) {
        int i = tid + j * 256;
        double dx = (double)xb[i], dy = (double)xb[N_ + i], dz = (double)xb[2 * N_ + i];
        xs[i] = dx; ys[i] = dy; zs[i] = dz;
        x64[j] = dx; y64[j] = dy; z64[j] = dz;
        q64[j] = dx * dx + dy * dy + dz * dz;
        dist[j] = 1e30;
    }
    if (tid < 2) cand[tid] = 0ull;
    __syncthreads();

    int far = 0;
    int f0 = 0, f1 = 0, f2 = 0, f3 = 0;
    for (int s = 0; s < 1023; ++s) {
        int sk = s >> 8;                    // uniform -> SALU branch
        int sl = s & 255;
        if (sk == 0)      f0 = (tid == sl) ? far : f0;
        else if (sk == 1) f1 = (tid == sl) ? far : f1;
        else if (sk == 2) f2 = (tid == sl) ? far : f2;
        else              f3 = (tid == sl) ? far : f3;

        double cx = xs[far], cy = ys[far], cz = zs[far];
        double c2p = cx * cx + cy * cy + cz * cz + 1.0;
        double A = -2.0 * cx, Bc = -2.0 * cy, Cc = -2.0 * cz;
#pragma unroll
        for (int j = 0; j < 16; ++j) {
            double d = fma(A, x64[j], fma(Bc, y64[j], fma(Cc, z64[j], q64[j] + c2p)));
            dist[j] = fmin(dist[j], packd(d, tid | (j << 8)));
        }
        double m[8];
#pragma unroll
        for (int j = 0; j < 8; ++j) m[j] = fmax(dist[2 * j], dist[2 * j + 1]);
        double m0 = fmax(fmax(m[0], m[1]), fmax(m[2], m[3]));
        double m1 = fmax(fmax(m[4], m[5]), fmax(m[6], m[7]));
        double k = fmax(m0, m1);
        k = dpp_max_f64<0x111>(k);   // row_shr:1
        k = dpp_max_f64<0x112>(k);   // row_shr:2
        k = dpp_max_f64<0x114>(k);   // row_shr:4
        k = dpp_max_f64<0x118>(k);   // row_shr:8
        k = dpp_max_f64<0x142>(k);   // row_bcast15
        k = dpp_max_f64<0x143>(k);   // row_bcast31
        int buf = s & 1;
        if (lane == 63)
            atomicMax(&cand[buf], (unsigned long long)__double_as_longlong(k));
        if (tid == 0) cand[buf ^ 1] = 0ull;     // reset other slot for next iter
        __syncthreads();
        unsigned lo = ((const unsigned*)cand)[buf * 2];
        far = (int)(__builtin_amdgcn_readfirstlane(lo) & 0xFFFu);
    }
    if (tid == 255) f3 = far;
    {
        float4 w0 = make_float4((float)xs[f0], (float)ys[f0], (float)zs[f0], 0.f);
        out0[(size_t)b * 3072 + tid]        = w0.x;
        out0[(size_t)b * 3072 + 1024 + tid] = w0.y;
        out0[(size_t)b * 3072 + 2048 + tid] = w0.z;
        out0[(size_t)b * 3072 + 256 + tid]        = (float)xs[f1];
        out0[(size_t)b * 3072 + 1024 + 256 + tid] = (float)ys[f1];
        out0[(size_t)b * 3072 + 2048 + 256 + tid] = (float)zs[f1];
        out0[(size_t)b * 3072 + 512 + tid]        = (float)xs[f2];
        out0[(size_t)b * 3072 + 1024 + 512 + tid] = (float)ys[f2];
        out0[(size_t)b * 3072 + 2048 + 512 + tid] = (float)zs[f2];
        out0[(size_t)b * 3072 + 768 + tid]        = (float)xs[f3];
        out0[(size_t)b * 3072 + 1024 + 768 + tid] = (float)ys[f3];
        out0[(size_t)b * 3072 + 2048 + 768 + tid] = (float)zs[f3];
    }
}

// ---------------------------------------------------------------- prologue: weights->bf16, xyz->double4{x,y,z,|p|^2}
__global__ __launch_bounds__(256) void prep_kernel(const float* __restrict__ xyz,
                                                   const float* __restrict__ W1,
                                                   const float* __restrict__ W2,
                                                   u16* __restrict__ W1bf,
                                                   u16* __restrict__ W2bf,
                                                   double4* __restrict__ xyzq) {
    int t = blockIdx.x * 256 + threadIdx.x;   // grid 256 blocks -> t < 65536
    if (t < 4096) W1bf[t] = f2bf(W1[t]);
    if (t < 8192) W2bf[t] = f2bf(W2[t]);
    int b = t >> 12, i = t & 4095;
    const float* xb = xyz + (size_t)b * 3 * N_;
    double x = (double)xb[i], y = (double)xb[N_ + i], z = (double)xb[2 * N_ + i];
    double4 v; v.x = x; v.y = y; v.z = z; v.w = x * x + y * y + z * z;
    xyzq[t] = v;
}

// ---------------------------------------------------------------- ball query
// one wave per centroid; first-32-ascending-index semantics via ballot compaction
__global__ __launch_bounds__(256) void ballq_kernel(const double4* __restrict__ xyzq,
                                                    const float* __restrict__ out0,
                                                    int* __restrict__ idxbuf) {
    int wid = threadIdx.x >> 6, lane = threadIdx.x & 63;
    int m = blockIdx.x * 4 + wid;          // centroid id < 16384
    int b = m >> 10, s = m & 1023;
    const double4* pb = xyzq + (size_t)b * N_;
    double cx = (double)out0[b * 3072 + s];
    double cy = (double)out0[b * 3072 + 1024 + s];
    double cz = (double)out0[b * 3072 + 2048 + s];
    double c2 = cx * cx + cy * cy + cz * cz;
    const double rr = 0.4 * 0.4;
    int* ob = idxbuf + (size_t)m * K_;
    int cnt = 0, first = -1;
    for (int ch = 0; ch < N_ / 64; ++ch) {
        int i = ch * 64 + lane;
        double4 p = pb[i];
        double dot = cx * p.x + cy * p.y + cz * p.z;
        double sqr = (c2 + p.w) - 2.0 * dot;
        bool in = !(sqr > rr);
        unsigned long long mask = __ballot(in);
        if (in) {
            int pos = cnt + __popcll(mask & ((1ull << lane) - 1ull));
            if (pos < K_) ob[pos] = i;
        }
        if (cnt == 0 && mask) first = ch * 64 + (__ffsll((long long)mask) - 1);
        cnt += __popcll(mask);
        if (cnt >= K_) break;
    }
    if (cnt < K_ && lane >= cnt && lane < K_) ob[lane] = first;
}

// ---------------------------------------------------------------- gather + layer0 stats
__global__ __launch_bounds__(256) void gather_stats0(
        const float* __restrict__ xyz, const float* __restrict__ pts,
        const float* __restrict__ out0, const int* __restrict__ idxbuf,
        const float* __restrict__ W0, const float* __restrict__ b0,
        float* __restrict__ F, float2* __restrict__ part) {
    __shared__ float Fs[64][6];
    __shared__ float W0s[384];
    __shared__ float b0s[64];
    __shared__ float2 red[4][64];
    int tid = threadIdx.x;
    long rowbase = (long)blockIdx.x * 64;
    if (tid < 64) {
        long r = rowbase + tid;
        int b = (int)(r >> 15);
        int rem = (int)(r & 32767);
        int s = rem >> 5;
        int i = idxbuf[r];
        const float* xb = xyz + (size_t)b * 3 * N_;
        const float* pb = pts + (size_t)b * 3 * N_;
        float cx = out0[b * 3072 + s], cy = out0[b * 3072 + 1024 + s], cz = out0[b * 3072 + 2048 + s];
        float f[6];
        f[0] = xb[i] - cx; f[1] = xb[N_ + i] - cy; f[2] = xb[2 * N_ + i] - cz;
        f[3] = pb[i];      f[4] = pb[N_ + i];      f[5] = pb[2 * N_ + i];
        float* Fg = F + (size_t)r * 6;
#pragma unroll
        for (int c = 0; c < 6; ++c) { Fs[tid][c] = f[c]; Fg[c] = f[c]; }
        b0s[tid] = b0[tid];
    }
    for (int t = tid; t < 384; t += 256) W0s[t] = W0[t];
    __syncthreads();
    int o = tid & 63, rg = tid >> 6;
    float w[6];
#pragma unroll
    for (int c = 0; c < 6; ++c) w[c] = W0s[o * 6 + c];
    float sum = 0.f, sq = 0.f;
#pragma unroll
    for (int rr = 0; rr < 16; ++rr) {
        int rl = rg * 16 + rr;
        float y = b0s[o];
#pragma unroll
        for (int c = 0; c < 6; ++c) y += Fs[rl][c] * w[c];
        sum += y; sq += y * y;
    }
    red[rg][o] = make_float2(sum, sq);
    __syncthreads();
    if (tid < 64) {
        float2 t0 = red[0][tid], t1 = red[1][tid], t2 = red[2][tid], t3 = red[3][tid];
        part[(size_t)blockIdx.x * 64 + tid] =
            make_float2(t0.x + t1.x + t2.x + t3.x, t0.y + t1.y + t2.y + t3.y);
    }
}

// ---------------------------------------------------------------- BN stats reduce
__global__ __launch_bounds__(256) void reduce_stats(const float2* __restrict__ part,
                                                    int nblk, int C,
                                                    const float* __restrict__ g,
                                                    const float* __restrict__ beta,
                                                    float* __restrict__ scale,
                                                    float* __restrict__ shift) {
    int o = blockIdx.x;
    int tid = threadIdx.x;
    double s = 0.0, q = 0.0;
    for (int i = tid; i < nblk; i += 256) {
        float2 v = part[(size_t)i * C + o];
        s += (double)v.x; q += (double)v.y;
    }
    __shared__ double ss[256], qq[256];
    ss[tid] = s; qq[tid] = q;
    __syncthreads();
    for (int m = 128; m > 0; m >>= 1) {
        if (tid < m) { ss[tid] += ss[tid + m]; qq[tid] += qq[tid + m]; }
        __syncthreads();
    }
    if (tid == 0) {
        const double Rd = (double)R_;
        double mean = ss[0] / Rd;
        double var = qq[0] / Rd - mean * mean;
        double sc = (double)g[o] / sqrt(var + 1e-5);
        scale[o] = (float)sc;
        shift[o] = (float)((double)beta[o] - mean * sc);
    }
}

// ---------------------------------------------------------------- layer1 stats: F -> X1 -> GEMM1 -> y1 stats (no Y1 store)
__global__ __launch_bounds__(256) void layer1_mfma(
        const float* __restrict__ F, const float* __restrict__ W0,
        const float* __restrict__ b0, const float* __restrict__ scale0,
        const float* __restrict__ shift0, const u16* __restrict__ W1bf,
        const float* __restrict__ b1, float2* __restrict__ part) {
    __shared__ float Fs[64][6];
    __shared__ float W0s[384];
    __shared__ float b0s[64], sc0[64], sh0[64];
    __shared__ u16 Xs[64][72];
    __shared__ float ssum[16][64];
    __shared__ float ssq[16][64];
    int tid = threadIdx.x;
    long rowbase = (long)blockIdx.x * 64;
    for (int t = tid; t < 384; t += 256) { Fs[t / 6][t % 6] = F[rowbase * 6 + t]; W0s[t] = W0[t]; }
    if (tid < 64) { b0s[tid] = b0[tid]; sc0[tid] = scale0[tid]; sh0[tid] = shift0[tid]; }
    __syncthreads();
    {
        int o = tid & 63, rg = tid >> 6;
        float w[6];
#pragma unroll
        for (int c = 0; c < 6; ++c) w[c] = W0s[o * 6 + c];
        float sc = sc0[o], sh = sh0[o], bb = b0s[o];
#pragma unroll
        for (int rr = 0; rr < 16; ++rr) {
            int rl = rg * 16 + rr;
            float y = bb;
#pragma unroll
            for (int c = 0; c < 6; ++c) y += Fs[rl][c] * w[c];
            Xs[rl][o] = f2bf(fmaxf(sc * y + sh, 0.f));
        }
    }
    __syncthreads();
    int l = tid & 63, w = tid >> 6;
    int ar = l & 15, kg = l >> 4;
    bf16x8 a0 = *(const bf16x8*)&Xs[w * 16 + ar][kg * 8];
    bf16x8 a1 = *(const bf16x8*)&Xs[w * 16 + ar][32 + kg * 8];
    f32x4 acc[4];
#pragma unroll
    for (int t4 = 0; t4 < 4; ++t4) acc[t4] = (f32x4){0.f, 0.f, 0.f, 0.f};
#pragma unroll
    for (int t4 = 0; t4 < 4; ++t4) {
        const u16* wp = &W1bf[(t4 * 16 + ar) * 64 + kg * 8];
        bf16x8 bfr0 = *(const bf16x8*)wp;
        bf16x8 bfr1 = *(const bf16x8*)(wp + 32);
        acc[t4] = __builtin_amdgcn_mfma_f32_16x16x32_bf16(a0, bfr0, acc[t4], 0, 0, 0);
        acc[t4] = __builtin_amdgcn_mfma_f32_16x16x32_bf16(a1, bfr1, acc[t4], 0, 0, 0);
    }
#pragma unroll
    for (int t4 = 0; t4 < 4; ++t4) {
        int col = t4 * 16 + ar;
        float bb = b1[col];
        float s = 0.f, q = 0.f;
#pragma unroll
        for (int r = 0; r < 4; ++r) {
            float y = acc[t4][r] + bb;
            s += y; q += y * y;
        }
        ssum[w * 4 + kg][col] = s;
        ssq[w * 4 + kg][col] = q;
    }
    __syncthreads();
    if (tid < 64) {
        float s = 0.f, q = 0.f;
#pragma unroll
        for (int i = 0; i < 16; ++i) { s += ssum[i][tid]; q += ssq[i][tid]; }
        part[(size_t)blockIdx.x * 64 + tid] = make_float2(s, q);
    }
}

// ---------------------------------------------------------------- layer2: F -> X1 -> GEMM1 -> BN1+relu -> X2 -> GEMM2 -> max/min + stats
__global__ __launch_bounds__(256) void layer2_mfma(
        const float* __restrict__ F, const float* __restrict__ W0,
        const float* __restrict__ b0, const float* __restrict__ scale0,
        const float* __restrict__ shift0, const u16* __restrict__ W1bf,
        const float* __restrict__ b1, const float* __restrict__ scale1,
        const float* __restrict__ shift1, const u16* __restrict__ W2bf,
        const float* __restrict__ b2, float* __restrict__ gmax,
        float* __restrict__ gmin, float2* __restrict__ part) {
    __shared__ float Fs[64][6];
    __shared__ float W0s[384];
    __shared__ float b0s[64], sc0[64], sh0[64], b1s[64], sc1s[64], sh1s[64];
    __shared__ u16 Xs[64][72];
    __shared__ float mxs[16][128], mns[16][128];
    __shared__ float ssum[16][128], ssq[16][128];
    int tid = threadIdx.x;
    long rowbase = (long)blockIdx.x * 64;
    for (int t = tid; t < 384; t += 256) { Fs[t / 6][t % 6] = F[rowbase * 6 + t]; W0s[t] = W0[t]; }
    if (tid < 64) {
        b0s[tid] = b0[tid]; sc0[tid] = scale0[tid]; sh0[tid] = shift0[tid];
        b1s[tid] = b1[tid]; sc1s[tid] = scale1[tid]; sh1s[tid] = shift1[tid];
    }
    __syncthreads();
    {   // X1 = relu(bn0(F W0^T + b0))
        int o = tid & 63, rg = tid >> 6;
        float w[6];
#pragma unroll
        for (int c = 0; c < 6; ++c) w[c] = W0s[o * 6 + c];
        float sc = sc0[o], sh = sh0[o], bb = b0s[o];
#pragma unroll
        for (int rr = 0; rr < 16; ++rr) {
            int rl = rg * 16 + rr;
            float y = bb;
#pragma unroll
            for (int c = 0; c < 6; ++c) y += Fs[rl][c] * w[c];
            Xs[rl][o] = f2bf(fmaxf(sc * y + sh, 0.f));
        }
    }
    __syncthreads();
    int l = tid & 63, w = tid >> 6;
    int ar = l & 15, kg = l >> 4;
    {   // GEMM1 + BN1 + relu -> X2 (reuse Xs)
        bf16x8 a0 = *(const bf16x8*)&Xs[w * 16 + ar][kg * 8];
        bf16x8 a1 = *(const bf16x8*)&Xs[w * 16 + ar][32 + kg * 8];
        f32x4 acc1[4];
#pragma unroll
        for (int t4 = 0; t4 < 4; ++t4) acc1[t4] = (f32x4){0.f, 0.f, 0.f, 0.f};
#pragma unroll
        for (int t4 = 0; t4 < 4; ++t4) {
            const u16* wp = &W1bf[(t4 * 16 + ar) * 64 + kg * 8];
            bf16x8 bfr0 = *(const bf16x8*)wp;
            bf16x8 bfr1 = *(const bf16x8*)(wp + 32);
            acc1[t4] = __builtin_amdgcn_mfma_f32_16x16x32_bf16(a0, bfr0, acc1[t4], 0, 0, 0);
            acc1[t4] = __builtin_amdgcn_mfma_f32_16x16x32_bf16(a1, bfr1, acc1[t4], 0, 0, 0);
        }
        __syncthreads();   // all GEMM1 reads of Xs complete
#pragma unroll
        for (int t4 = 0; t4 < 4; ++t4) {
            int col = t4 * 16 + ar;
            float bb = b1s[col], sc = sc1s[col], sh = sh1s[col];
#pragma unroll
            for (int r = 0; r < 4; ++r) {
                float y = acc1[t4][r] + bb;
                Xs[w * 16 + kg * 4 + r][col] = f2bf(fmaxf(sc * y + sh, 0.f));
            }
        }
    }
    __syncthreads();
    bf16x8 a0 = *(const bf16x8*)&Xs[w * 16 + ar][kg * 8];
    bf16x8 a1 = *(const bf16x8*)&Xs[w * 16 + ar][32 + kg * 8];
    f32x4 acc[8];
#pragma unroll
    for (int t8 = 0; t8 < 8; ++t8) acc[t8] = (f32x4){0.f, 0.f, 0.f, 0.f};
#pragma unroll
    for (int t8 = 0; t8 < 8; ++t8) {
        const u16* wp = &W2bf[(t8 * 16 + ar) * 64 + kg * 8];
        bf16x8 bfr0 = *(const bf16x8*)wp;
        bf16x8 bfr1 = *(const bf16x8*)(wp + 32);
        acc[t8] = __builtin_amdgcn_mfma_f32_16x16x32_bf16(a0, bfr0, acc[t8], 0, 0, 0);
        acc[t8] = __builtin_amdgcn_mfma_f32_16x16x32_bf16(a1, bfr1, acc[t8], 0, 0, 0);
    }
#pragma unroll
    for (int t8 = 0; t8 < 8; ++t8) {
        int col = t8 * 16 + ar;
        float bb = b2[col];
        float y0 = acc[t8][0] + bb, y1 = acc[t8][1] + bb;
        float y2 = acc[t8][2] + bb, y3 = acc[t8][3] + bb;
        ssum[w * 4 + kg][col] = y0 + y1 + y2 + y3;
        ssq[w * 4 + kg][col] = y0 * y0 + y1 * y1 + y2 * y2 + y3 * y3;
        mxs[w * 4 + kg][col] = fmaxf(fmaxf(y0, y1), fmaxf(y2, y3));
        mns[w * 4 + kg][col] = fminf(fminf(y0, y1), fminf(y2, y3));
    }
    __syncthreads();
    if (tid < 128) {
        int col = tid;
        float s = 0.f, q = 0.f;
        float m0 = -3.0e38f, m1 = -3.0e38f, n0 = 3.0e38f, n1 = 3.0e38f;
#pragma unroll
        for (int i = 0; i < 8; ++i) {
            s += ssum[i][col]; q += ssq[i][col];
            m0 = fmaxf(m0, mxs[i][col]); n0 = fminf(n0, mns[i][col]);
        }
#pragma unroll
        for (int i = 8; i < 16; ++i) {
            s += ssum[i][col]; q += ssq[i][col];
            m1 = fmaxf(m1, mxs[i][col]); n1 = fminf(n1, mns[i][col]);
        }
        part[(size_t)blockIdx.x * 128 + col] = make_float2(s, q);
        gmax[((size_t)blockIdx.x * 2 + 0) * 128 + col] = m0;
        gmax[((size_t)blockIdx.x * 2 + 1) * 128 + col] = m1;
        gmin[((size_t)blockIdx.x * 2 + 0) * 128 + col] = n0;
        gmin[((size_t)blockIdx.x * 2 + 1) * 128 + col] = n1;
    }
}

// ---------------------------------------------------------------- final BN2 + relu + transpose
__global__ __launch_bounds__(256) void final_kernel(const float* __restrict__ gmax,
                                                    const float* __restrict__ gmin,
                                                    const float* __restrict__ scale2,
                                                    const float* __restrict__ shift2,
                                                    float* __restrict__ out1) {
    int b = blockIdx.x, st = blockIdx.y, ot = blockIdx.z;
    __shared__ float tile[32][33];
    int tid = threadIdx.x;
    for (int e = tid; e < 1024; e += 256) {
        int sl = e >> 5, ol = e & 31;
        int s = st * 32 + sl, o = ot * 32 + ol;
        size_t m = (size_t)b * 1024 + s;
        float sc = scale2[o];
        float v = (sc >= 0.f) ? gmax[m * 128 + o] : gmin[m * 128 + o];
        tile[sl][ol] = fmaxf(sc * v + shift2[o], 0.f);
    }
    __syncthreads();
    for (int e = tid; e < 1024; e += 256) {
        int ol = e >> 5, sl = e & 31;
        int s = st * 32 + sl, o = ot * 32 + ol;
        out1[(size_t)b * 131072 + (size_t)o * 1024 + s] = tile[sl][ol];
    }
}

// ---------------------------------------------------------------- launch
extern "C" void kernel_launch(void* const* d_in, const int* in_sizes, int n_in,
                              void* d_out, int out_size, void* d_ws, size_t ws_size,
                              hipStream_t stream) {
    const float* xyz   = (const float*)d_in[0];
    const float* pts   = (const float*)d_in[1];
    const float* W0    = (const float*)d_in[2];
    const float* b0    = (const float*)d_in[3];
    const float* g0    = (const float*)d_in[4];
    const float* beta0 = (const float*)d_in[5];
    const float* W1    = (const float*)d_in[6];
    const float* b1    = (const float*)d_in[7];
    const float* g1    = (const float*)d_in[8];
    const float* beta1 = (const float*)d_in[9];
    const float* W2    = (const float*)d_in[10];
    const float* b2    = (const float*)d_in[11];
    const float* g2    = (const float*)d_in[12];
    const float* beta2 = (const float*)d_in[13];

    float* out0 = (float*)d_out;                  // (B,3,1024)  = 49152
    float* out1 = (float*)d_out + 49152;          // (B,128,1024)

    char* w = (char*)d_ws;
    size_t off = 0;
    double4* xyzq = (double4*)(w + off);  off += (size_t)B_ * N_ * 32;   // 2 MB, 32B aligned
    int*    idxbuf = (int*)(w + off);    off += (size_t)R_ * 4;
    float*  F      = (float*)(w + off);  off += (size_t)R_ * 6 * 4;
    float*  gmax   = (float*)(w + off);  off += (size_t)B_ * S_ * 128 * 4;
    float*  gmin   = (float*)(w + off);  off += (size_t)B_ * S_ * 128 * 4;
    float2* part   = (float2*)(w + off); off += (size_t)NBLK_ * 128 * 2 * 4;
    u16*    W1bf   = (u16*)(w + off);    off += 4096 * 2;
    u16*    W2bf   = (u16*)(w + off);    off += 8192 * 2;
    float*  ss     = (float*)(w + off);  off += 512 * 4;
    float* scale0 = ss,       *shift0 = ss + 64;
    float* scale1 = ss + 128, *shift1 = ss + 192;
    float* scale2 = ss + 256, *shift2 = ss + 384;

    prep_kernel<<<256, 256, 0, stream>>>(xyz, W1, W2, W1bf, W2bf, xyzq);
    fps_kernel<<<B_, 256, 0, stream>>>(xyz, out0);
    ballq_kernel<<<(B_ * S_) / 4, 256, 0, stream>>>(xyzq, out0, idxbuf);
    gather_stats0<<<NBLK_, 256, 0, stream>>>(xyz, pts, out0, idxbuf, W0, b0, F, part);
    reduce_stats<<<64, 256, 0, stream>>>(part, NBLK_, 64, g0, beta0, scale0, shift0);
    layer1_mfma<<<NBLK_, 256, 0, stream>>>(F, W0, b0, scale0, shift0, W1bf, b1, part);
    reduce_stats<<<64, 256, 0, stream>>>(part, NBLK_, 64, g1, beta1, scale1, shift1);
    layer2_mfma<<<NBLK_, 256, 0, stream>>>(F, W0, b0, scale0, shift0, W1bf, b1,
                                           scale1, shift1, W2bf, b2, gmax, gmin, part);
    reduce_stats<<<128, 256, 0, stream>>>(part, NBLK_, 128, g2, beta2, scale2, shift2);
    final_kernel<<<dim3(B_, 32, 4), 256, 0, stream>>>(gmax, gmin, scale2, shift2, out1);
}

// Round 8
// 925.219 us; speedup vs baseline: 1.0689x; 1.0689x over previous
//
#include <hip/hip_runtime.h>
#include <hip/hip_bf16.h>

#define B_ 16
#define N_ 4096
#define S_ 1024
#define K_ 32
#define R_ (B_*S_*K_)   // 524288 rows
#define NBLK_ (R_/64)   // 8192 row-tiles of 64

typedef unsigned short u16;
typedef __attribute__((ext_vector_type(8))) short bf16x8;
typedef __attribute__((ext_vector_type(4))) float f32x4;

__device__ __forceinline__ u16 f2bf(float f) {
    __hip_bfloat16 h = __float2bfloat16(f);
    return __builtin_bit_cast(u16, h);
}
__device__ __forceinline__ float bf2f(u16 u) {
    unsigned x = ((unsigned)u) << 16;
    return __builtin_bit_cast(float, x);
}

// fmax(v, dpp_move<CTRL>(v)) on f64; identity-preserving (old=own, bound_ctrl=0).
template <int CTRL>
__device__ __forceinline__ double dpp_max_f64(double v) {
    unsigned long long b = (unsigned long long)__double_as_longlong(v);
    int lo = (int)(unsigned)b;
    int hi = (int)(unsigned)(b >> 32);
    int olo = __builtin_amdgcn_update_dpp(lo, lo, CTRL, 0xF, 0xF, false);
    int ohi = __builtin_amdgcn_update_dpp(hi, hi, CTRL, 0xF, 0xF, false);
    double o = __longlong_as_double(
        (long long)(((unsigned long long)(unsigned)ohi << 32) | (unsigned)olo));
    return fmax(v, o);
}

// replace low 12 mantissa bits of positive double with idx (order-preserving key)
__device__ __forceinline__ double packd(double d, int idx) {
    unsigned long long b = (unsigned long long)__double_as_longlong(d);
    b = (b & ~0xFFFull) | (unsigned)idx;
    return __longlong_as_double((long long)b);
}

// ---------------------------------------------------------------- FPS
// one block per batch, 512 threads (8 waves), 8 points/thread, f64 distances
// (+1.0 biased -> positive). dist[] stores PACKED keys (idx in low 12 mantissa
// bits). Per iter: 7-op fmax tree, 6-level DPP butterfly (lane63 = wave max),
// one ds_max_u64 per wave into a single rotating slot (3-slot rotation makes
// the reset provably barrier-ordered vs readers), one barrier, broadcast b32
// read + readfirstlane -> far. out0 written in epilogue from far history.
__global__ __launch_bounds__(512, 2) void fps_kernel(const float* __restrict__ xyz,
                                                     float* __restrict__ out0) {
    const int b = blockIdx.x;
    const int tid = threadIdx.x;
    const int lane = tid & 63;
    __shared__ float4 p4[N_];
    __shared__ unsigned long long cand[3];
    const float* xb = xyz + (size_t)b * 3 * N_;

    double x64[8], y64[8], z64[8], q64[8], dist[8];
#pragma unroll
    for (int j = 0; j < 8; ++j) {
        int i = tid + j * 512;
        float x = xb[i], y = xb[N_ + i], z = xb[2 * N_ + i];
        p4[i] = make_float4(x, y, z, 0.f);
        x64[j] = (double)x; y64[j] = (double)y; z64[j] = (double)z;
        q64[j] = x64[j] * x64[j] + y64[j] * y64[j] + z64[j] * z64[j];
        dist[j] = 1e30;
    }
    if (tid < 3) cand[tid] = 0ull;
    __syncthreads();

    int far = 0;
    int f0 = 0, f1 = 0;
    int cur = 0;
    for (int s = 0; s < 1023; ++s) {
        float4 c = p4[far];
        f0 = (tid == s) ? far : f0;
        f1 = (tid + 512 == s) ? far : f1;
        double cx = (double)c.x, cy = (double)c.y, cz = (double)c.z;
        double c2p = cx * cx + cy * cy + cz * cz + 1.0;
        double A = -2.0 * cx, Bc = -2.0 * cy, Cc = -2.0 * cz;
#pragma unroll
        for (int j = 0; j < 8; ++j) {
            double d = fma(A, x64[j], fma(Bc, y64[j], fma(Cc, z64[j], q64[j] + c2p)));
            dist[j] = fmin(dist[j], packd(d, tid | (j << 9)));
        }
        double k = fmax(fmax(fmax(dist[0], dist[1]), fmax(dist[2], dist[3])),
                        fmax(fmax(dist[4], dist[5]), fmax(dist[6], dist[7])));
        k = dpp_max_f64<0x111>(k);   // row_shr:1
        k = dpp_max_f64<0x112>(k);   // row_shr:2
        k = dpp_max_f64<0x114>(k);   // row_shr:4
        k = dpp_max_f64<0x118>(k);   // row_shr:8
        k = dpp_max_f64<0x142>(k);   // row_bcast15
        k = dpp_max_f64<0x143>(k);   // row_bcast31
        int nxt = (cur == 2) ? 0 : cur + 1;
        if (lane == 63)
            atomicMax(&cand[cur], (unsigned long long)__double_as_longlong(k));
        if (tid == 0) cand[nxt] = 0ull;   // used at iter s+1; reset here is
                                          // barrier-ordered vs its iter s-1 readers
        __syncthreads();
        unsigned lo = ((const unsigned*)cand)[cur * 2];
        far = (int)(__builtin_amdgcn_readfirstlane(lo) & 0xFFFu);
        cur = nxt;
    }
    if (tid == 511) f1 = far;
    {
        float4 c0 = p4[f0];
        out0[(size_t)b * 3072 + tid]        = c0.x;
        out0[(size_t)b * 3072 + 1024 + tid] = c0.y;
        out0[(size_t)b * 3072 + 2048 + tid] = c0.z;
        float4 c1 = p4[f1];
        out0[(size_t)b * 3072 + 512 + tid]        = c1.x;
        out0[(size_t)b * 3072 + 1024 + 512 + tid] = c1.y;
        out0[(size_t)b * 3072 + 2048 + 512 + tid] = c1.z;
    }
}

// ---------------------------------------------------------------- ball query
__global__ __launch_bounds__(256) void ballq_kernel(const float* __restrict__ xyz,
                                                    const float* __restrict__ out0,
                                                    int* __restrict__ idxbuf) {
    int wid = threadIdx.x >> 6, lane = threadIdx.x & 63;
    int m = blockIdx.x * 4 + wid;          // centroid id < 16384
    int b = m >> 10, s = m & 1023;
    const float* xb = xyz + (size_t)b * 3 * N_;
    double cx = (double)out0[b * 3072 + s];
    double cy = (double)out0[b * 3072 + 1024 + s];
    double cz = (double)out0[b * 3072 + 2048 + s];
    double c2 = cx * cx + cy * cy + cz * cz;
    const double rr = 0.4 * 0.4;
    int* ob = idxbuf + (size_t)m * K_;
    int cnt = 0, first = -1;
    for (int ch = 0; ch < N_ / 64; ++ch) {
        int i = ch * 64 + lane;
        double x = (double)xb[i], y = (double)xb[N_ + i], z = (double)xb[2 * N_ + i];
        double p2 = x * x + y * y + z * z;
        double dot = cx * x + cy * y + cz * z;
        double sqr = (c2 + p2) - 2.0 * dot;
        bool in = !(sqr > rr);
        unsigned long long mask = __ballot(in);
        if (in) {
            int pos = cnt + __popcll(mask & ((1ull << lane) - 1ull));
            if (pos < K_) ob[pos] = i;
        }
        if (cnt == 0 && mask) first = ch * 64 + (__ffsll((long long)mask) - 1);
        cnt += __popcll(mask);
        if (cnt >= K_) break;
    }
    if (cnt < K_ && lane >= cnt && lane < K_) ob[lane] = first;
}

// ---------------------------------------------------------------- gather + layer0 stats
__global__ __launch_bounds__(256) void gather_stats0(
        const float* __restrict__ xyz, const float* __restrict__ pts,
        const float* __restrict__ out0, const int* __restrict__ idxbuf,
        const float* __restrict__ W0, const float* __restrict__ b0,
        float* __restrict__ F, float2* __restrict__ part) {
    __shared__ float Fs[64][6];
    __shared__ float W0s[384];
    __shared__ float b0s[64];
    __shared__ float2 red[4][64];
    int tid = threadIdx.x;
    long rowbase = (long)blockIdx.x * 64;
    if (tid < 64) {
        long r = rowbase + tid;
        int b = (int)(r >> 15);
        int rem = (int)(r & 32767);
        int s = rem >> 5;
        int i = idxbuf[r];
        const float* xb = xyz + (size_t)b * 3 * N_;
        const float* pb = pts + (size_t)b * 3 * N_;
        float cx = out0[b * 3072 + s], cy = out0[b * 3072 + 1024 + s], cz = out0[b * 3072 + 2048 + s];
        float f[6];
        f[0] = xb[i] - cx; f[1] = xb[N_ + i] - cy; f[2] = xb[2 * N_ + i] - cz;
        f[3] = pb[i];      f[4] = pb[N_ + i];      f[5] = pb[2 * N_ + i];
        float* Fg = F + (size_t)r * 6;
#pragma unroll
        for (int c = 0; c < 6; ++c) { Fs[tid][c] = f[c]; Fg[c] = f[c]; }
        b0s[tid] = b0[tid];
    }
    for (int t = tid; t < 384; t += 256) W0s[t] = W0[t];
    __syncthreads();
    int o = tid & 63, rg = tid >> 6;
    float w[6];
#pragma unroll
    for (int c = 0; c < 6; ++c) w[c] = W0s[o * 6 + c];
    float sum = 0.f, sq = 0.f;
#pragma unroll
    for (int rr = 0; rr < 16; ++rr) {
        int rl = rg * 16 + rr;
        float y = b0s[o];
#pragma unroll
        for (int c = 0; c < 6; ++c) y += Fs[rl][c] * w[c];
        sum += y; sq += y * y;
    }
    red[rg][o] = make_float2(sum, sq);
    __syncthreads();
    if (tid < 64) {
        float2 t0 = red[0][tid], t1 = red[1][tid], t2 = red[2][tid], t3 = red[3][tid];
        part[(size_t)blockIdx.x * 64 + tid] =
            make_float2(t0.x + t1.x + t2.x + t3.x, t0.y + t1.y + t2.y + t3.y);
    }
}

// ---------------------------------------------------------------- BN stats reduce
__global__ __launch_bounds__(256) void reduce_stats(const float2* __restrict__ part,
                                                    int nblk, int C,
                                                    const float* __restrict__ g,
                                                    const float* __restrict__ beta,
                                                    float* __restrict__ scale,
                                                    float* __restrict__ shift) {
    int o = blockIdx.x;
    int tid = threadIdx.x;
    double s = 0.0, q = 0.0;
    for (int i = tid; i < nblk; i += 256) {
        float2 v = part[(size_t)i * C + o];
        s += (double)v.x; q += (double)v.y;
    }
    __shared__ double ss[256], qq[256];
    ss[tid] = s; qq[tid] = q;
    __syncthreads();
    for (int m = 128; m > 0; m >>= 1) {
        if (tid < m) { ss[tid] += ss[tid + m]; qq[tid] += qq[tid + m]; }
        __syncthreads();
    }
    if (tid == 0) {
        const double Rd = (double)R_;
        double mean = ss[0] / Rd;
        double var = qq[0] / Rd - mean * mean;
        double sc = (double)g[o] / sqrt(var + 1e-5);
        scale[o] = (float)sc;
        shift[o] = (float)((double)beta[o] - mean * sc);
    }
}

// ---------------------------------------------------------------- weight f32->bf16 prologue
__global__ __launch_bounds__(256) void cvt_w_kernel(const float* __restrict__ W1,
                                                    const float* __restrict__ W2,
                                                    u16* __restrict__ W1bf,
                                                    u16* __restrict__ W2bf) {
    int t = blockIdx.x * 256 + threadIdx.x;    // grid = 32 blocks -> t < 8192
    if (t < 4096) W1bf[t] = f2bf(W1[t]);
    W2bf[t] = f2bf(W2[t]);
}

// ---------------------------------------------------------------- layer1: recompute layer0+BN0+relu -> bf16 MFMA GEMM (64x64) -> Y1 bf16 + stats
__global__ __launch_bounds__(256) void layer1_mfma(
        const float* __restrict__ F, const float* __restrict__ W0,
        const float* __restrict__ b0, const float* __restrict__ scale0,
        const float* __restrict__ shift0, const u16* __restrict__ W1bf,
        const float* __restrict__ b1, u16* __restrict__ Y1bf,
        float2* __restrict__ part) {
    __shared__ float Fs[64][6];
    __shared__ float W0s[384];
    __shared__ float b0s[64], sc0[64], sh0[64];
    __shared__ u16 Xs[64][72];
    __shared__ float ssum[16][64];
    __shared__ float ssq[16][64];
    int tid = threadIdx.x;
    long rowbase = (long)blockIdx.x * 64;
    for (int t = tid; t < 384; t += 256) { Fs[t / 6][t % 6] = F[rowbase * 6 + t]; W0s[t] = W0[t]; }
    if (tid < 64) { b0s[tid] = b0[tid]; sc0[tid] = scale0[tid]; sh0[tid] = shift0[tid]; }
    __syncthreads();
    {   // X1 = relu(bn0(F W0^T + b0)) -> bf16 tile
        int o = tid & 63, rg = tid >> 6;
        float w[6];
#pragma unroll
        for (int c = 0; c < 6; ++c) w[c] = W0s[o * 6 + c];
        float sc = sc0[o], sh = sh0[o], bb = b0s[o];
#pragma unroll
        for (int rr = 0; rr < 16; ++rr) {
            int rl = rg * 16 + rr;
            float y = bb;
#pragma unroll
            for (int c = 0; c < 6; ++c) y += Fs[rl][c] * w[c];
            Xs[rl][o] = f2bf(fmaxf(sc * y + sh, 0.f));
        }
    }
    __syncthreads();
    int l = tid & 63, w = tid >> 6;
    int ar = l & 15, kg = l >> 4;     // A row / k-group (also C col / row-group)
    bf16x8 a0 = *(const bf16x8*)&Xs[w * 16 + ar][kg * 8];
    bf16x8 a1 = *(const bf16x8*)&Xs[w * 16 + ar][32 + kg * 8];
    f32x4 acc[4];
#pragma unroll
    for (int t4 = 0; t4 < 4; ++t4) acc[t4] = (f32x4){0.f, 0.f, 0.f, 0.f};
#pragma unroll
    for (int t4 = 0; t4 < 4; ++t4) {
        const u16* wp = &W1bf[(t4 * 16 + ar) * 64 + kg * 8];
        bf16x8 bfr0 = *(const bf16x8*)wp;
        bf16x8 bfr1 = *(const bf16x8*)(wp + 32);
        acc[t4] = __builtin_amdgcn_mfma_f32_16x16x32_bf16(a0, bfr0, acc[t4], 0, 0, 0);
        acc[t4] = __builtin_amdgcn_mfma_f32_16x16x32_bf16(a1, bfr1, acc[t4], 0, 0, 0);
    }
#pragma unroll
    for (int t4 = 0; t4 < 4; ++t4) {
        int col = t4 * 16 + ar;
        float bb = b1[col];
        float s = 0.f, q = 0.f;
#pragma unroll
        for (int r = 0; r < 4; ++r) {
            float y = acc[t4][r] + bb;
            int row = w * 16 + kg * 4 + r;
            Y1bf[(rowbase + row) * 64 + col] = f2bf(y);
            s += y; q += y * y;
        }
        ssum[w * 4 + kg][col] = s;
        ssq[w * 4 + kg][col] = q;
    }
    __syncthreads();
    if (tid < 64) {
        float s = 0.f, q = 0.f;
#pragma unroll
        for (int i = 0; i < 16; ++i) { s += ssum[i][tid]; q += ssq[i][tid]; }
        part[(size_t)blockIdx.x * 64 + tid] = make_float2(s, q);
    }
}

// ---------------------------------------------------------------- layer2: BN1+relu -> bf16 MFMA GEMM (64x128) -> per-sample max/min + stats
__global__ __launch_bounds__(256) void layer2_mfma(
        const u16* __restrict__ Y1bf, const float* __restrict__ scale1,
        const float* __restrict__ shift1, const u16* __restrict__ W2bf,
        const float* __restrict__ b2, float* __restrict__ gmax,
        float* __restrict__ gmin, float2* __restrict__ part) {
    __shared__ u16 Xs[64][72];
    __shared__ float sc1s[64], sh1s[64];
    __shared__ float mxs[16][128], mns[16][128];
    __shared__ float ssum[16][128], ssq[16][128];
    int tid = threadIdx.x;
    long rowbase = (long)blockIdx.x * 64;
    if (tid < 64) { sc1s[tid] = scale1[tid]; sh1s[tid] = shift1[tid]; }
    __syncthreads();
    {   // X2 = relu(bn1(Y1)) -> bf16 tile; vectorized bf16 loads
        int r = tid >> 2, seg = (tid & 3) * 16;
        const u16* yp = &Y1bf[(rowbase + r) * 64 + seg];
        bf16x8 v0 = *(const bf16x8*)yp;
        bf16x8 v1 = *(const bf16x8*)(yp + 8);
#pragma unroll
        for (int j = 0; j < 8; ++j) {
            float x0 = fmaxf(sc1s[seg + j] * bf2f((u16)v0[j]) + sh1s[seg + j], 0.f);
            float x1 = fmaxf(sc1s[seg + 8 + j] * bf2f((u16)v1[j]) + sh1s[seg + 8 + j], 0.f);
            Xs[r][seg + j] = f2bf(x0);
            Xs[r][seg + 8 + j] = f2bf(x1);
        }
    }
    __syncthreads();
    int l = tid & 63, w = tid >> 6;
    int ar = l & 15, kg = l >> 4;
    bf16x8 a0 = *(const bf16x8*)&Xs[w * 16 + ar][kg * 8];
    bf16x8 a1 = *(const bf16x8*)&Xs[w * 16 + ar][32 + kg * 8];
    f32x4 acc[8];
#pragma unroll
    for (int t8 = 0; t8 < 8; ++t8) acc[t8] = (f32x4){0.f, 0.f, 0.f, 0.f};
#pragma unroll
    for (int t8 = 0; t8 < 8; ++t8) {
        const u16* wp = &W2bf[(t8 * 16 + ar) * 64 + kg * 8];
        bf16x8 bfr0 = *(const bf16x8*)wp;
        bf16x8 bfr1 = *(const bf16x8*)(wp + 32);
        acc[t8] = __builtin_amdgcn_mfma_f32_16x16x32_bf16(a0, bfr0, acc[t8], 0, 0, 0);
        acc[t8] = __builtin_amdgcn_mfma_f32_16x16x32_bf16(a1, bfr1, acc[t8], 0, 0, 0);
    }
#pragma unroll
    for (int t8 = 0; t8 < 8; ++t8) {
        int col = t8 * 16 + ar;
        float bb = b2[col];
        float y0 = acc[t8][0] + bb, y1 = acc[t8][1] + bb;
        float y2 = acc[t8][2] + bb, y3 = acc[t8][3] + bb;
        ssum[w * 4 + kg][col] = y0 + y1 + y2 + y3;
        ssq[w * 4 + kg][col] = y0 * y0 + y1 * y1 + y2 * y2 + y3 * y3;
        mxs[w * 4 + kg][col] = fmaxf(fmaxf(y0, y1), fmaxf(y2, y3));
        mns[w * 4 + kg][col] = fminf(fminf(y0, y1), fminf(y2, y3));
    }
    __syncthreads();
    if (tid < 128) {
        int col = tid;
        float s = 0.f, q = 0.f;
        float m0 = -3.0e38f, m1 = -3.0e38f, n0 = 3.0e38f, n1 = 3.0e38f;
#pragma unroll
        for (int i = 0; i < 8; ++i) {
            s += ssum[i][col]; q += ssq[i][col];
            m0 = fmaxf(m0, mxs[i][col]); n0 = fminf(n0, mns[i][col]);
        }
#pragma unroll
        for (int i = 8; i < 16; ++i) {
            s += ssum[i][col]; q += ssq[i][col];
            m1 = fmaxf(m1, mxs[i][col]); n1 = fminf(n1, mns[i][col]);
        }
        part[(size_t)blockIdx.x * 128 + col] = make_float2(s, q);
        gmax[((size_t)blockIdx.x * 2 + 0) * 128 + col] = m0;
        gmax[((size_t)blockIdx.x * 2 + 1) * 128 + col] = m1;
        gmin[((size_t)blockIdx.x * 2 + 0) * 128 + col] = n0;
        gmin[((size_t)blockIdx.x * 2 + 1) * 128 + col] = n1;
    }
}

// ---------------------------------------------------------------- final BN2 + relu + transpose
__global__ __launch_bounds__(256) void final_kernel(const float* __restrict__ gmax,
                                                    const float* __restrict__ gmin,
                                                    const float* __restrict__ scale2,
                                                    const float* __restrict__ shift2,
                                                    float* __restrict__ out1) {
    int b = blockIdx.x, st = blockIdx.y, ot = blockIdx.z;
    __shared__ float tile[32][33];
    int tid = threadIdx.x;
    for (int e = tid; e < 1024; e += 256) {
        int sl = e >> 5, ol = e & 31;
        int s = st * 32 + sl, o = ot * 32 + ol;
        size_t m = (size_t)b * 1024 + s;
        float sc = scale2[o];
        float v = (sc >= 0.f) ? gmax[m * 128 + o] : gmin[m * 128 + o];
        tile[sl][ol] = fmaxf(sc * v + shift2[o], 0.f);
    }
    __syncthreads();
    for (int e = tid; e < 1024; e += 256) {
        int ol = e >> 5, sl = e & 31;
        int s = st * 32 + sl, o = ot * 32 + ol;
        out1[(size_t)b * 131072 + (size_t)o * 1024 + s] = tile[sl][ol];
    }
}

// ---------------------------------------------------------------- launch
extern "C" void kernel_launch(void* const* d_in, const int* in_sizes, int n_in,
                              void* d_out, int out_size, void* d_ws, size_t ws_size,
                              hipStream_t stream) {
    const float* xyz   = (const float*)d_in[0];
    const float* pts   = (const float*)d_in[1];
    const float* W0    = (const float*)d_in[2];
    const float* b0    = (const float*)d_in[3];
    const float* g0    = (const float*)d_in[4];
    const float* beta0 = (const float*)d_in[5];
    const float* W1    = (const float*)d_in[6];
    const float* b1    = (const float*)d_in[7];
    const float* g1    = (const float*)d_in[8];
    const float* beta1 = (const float*)d_in[9];
    const float* W2    = (const float*)d_in[10];
    const float* b2    = (const float*)d_in[11];
    const float* g2    = (const float*)d_in[12];
    const float* beta2 = (const float*)d_in[13];

    float* out0 = (float*)d_out;                  // (B,3,1024)  = 49152
    float* out1 = (float*)d_out + 49152;          // (B,128,1024)

    char* w = (char*)d_ws;
    size_t off = 0;
    int*    idxbuf = (int*)(w + off);    off += (size_t)R_ * 4;
    float*  F      = (float*)(w + off);  off += (size_t)R_ * 6 * 4;
    u16*    Y1bf   = (u16*)(w + off);    off += (size_t)R_ * 64 * 2;
    float*  gmax   = (float*)(w + off);  off += (size_t)B_ * S_ * 128 * 4;
    float*  gmin   = (float*)(w + off);  off += (size_t)B_ * S_ * 128 * 4;
    float2* part   = (float2*)(w + off); off += (size_t)NBLK_ * 128 * 2 * 4;
    u16*    W1bf   = (u16*)(w + off);    off += 4096 * 2;
    u16*    W2bf   = (u16*)(w + off);    off += 8192 * 2;
    float*  ss     = (float*)(w + off);  off += 512 * 4;
    float* scale0 = ss,       *shift0 = ss + 64;
    float* scale1 = ss + 128, *shift1 = ss + 192;
    float* scale2 = ss + 256, *shift2 = ss + 384;

    cvt_w_kernel<<<32, 256, 0, stream>>>(W1, W2, W1bf, W2bf);
    fps_kernel<<<B_, 512, 0, stream>>>(xyz, out0);
    ballq_kernel<<<(B_ * S_) / 4, 256, 0, stream>>>(xyz, out0, idxbuf);
    gather_stats0<<<NBLK_, 256, 0, stream>>>(xyz, pts, out0, idxbuf, W0, b0, F, part);
    reduce_stats<<<64, 256, 0, stream>>>(part, NBLK_, 64, g0, beta0, scale0, shift0);
    layer1_mfma<<<NBLK_, 256, 0, stream>>>(F, W0, b0, scale0, shift0, W1bf, b1, Y1bf, part);
    reduce_stats<<<64, 256, 0, stream>>>(part, NBLK_, 64, g1, beta1, scale1, shift1);
    layer2_mfma<<<NBLK_, 256, 0, stream>>>(Y1bf, scale1, shift1, W2bf, b2, gmax, gmin, part);
    reduce_stats<<<128, 256, 0, stream>>>(part, NBLK_, 128, g2, beta2, scale2, shift2);
    final_kernel<<<dim3(B_, 32, 4), 256, 0, stream>>>(gmax, gmin, scale2, shift2, out1);
}

// Round 9
// 864.476 us; speedup vs baseline: 1.1441x; 1.0703x over previous
//
#include <hip/hip_runtime.h>
#include <hip/hip_bf16.h>

#define B_ 16
#define N_ 4096
#define S_ 1024
#define K_ 32
#define R_ (B_*S_*K_)   // 524288 rows
#define NBLK_ (R_/64)   // 8192 row-tiles of 64

typedef unsigned short u16;
typedef __attribute__((ext_vector_type(8))) short bf16x8;
typedef __attribute__((ext_vector_type(4))) float f32x4;

__device__ __forceinline__ u16 f2bf(float f) {
    __hip_bfloat16 h = __float2bfloat16(f);
    return __builtin_bit_cast(u16, h);
}
__device__ __forceinline__ float bf2f(u16 u) {
    unsigned x = ((unsigned)u) << 16;
    return __builtin_bit_cast(float, x);
}

// fmax(v, dpp_move<CTRL>(v)) on f64; identity-preserving (old=own, bound_ctrl=0).
template <int CTRL>
__device__ __forceinline__ double dpp_max_f64(double v) {
    unsigned long long b = (unsigned long long)__double_as_longlong(v);
    int lo = (int)(unsigned)b;
    int hi = (int)(unsigned)(b >> 32);
    int olo = __builtin_amdgcn_update_dpp(lo, lo, CTRL, 0xF, 0xF, false);
    int ohi = __builtin_amdgcn_update_dpp(hi, hi, CTRL, 0xF, 0xF, false);
    double o = __longlong_as_double(
        (long long)(((unsigned long long)(unsigned)ohi << 32) | (unsigned)olo));
    return fmax(v, o);
}

// replace low 12 mantissa bits of positive double with idx (order-preserving key)
__device__ __forceinline__ double packd(double d, int idx) {
    unsigned long long b = (unsigned long long)__double_as_longlong(d);
    b = (b & ~0xFFFull) | (unsigned)idx;
    return __longlong_as_double((long long)b);
}

// ---------------------------------------------------------------- FPS (round-6 measured optimum)
// one block per batch, 512 threads (8 waves), 8 points/thread, f64 distances
// (+1.0 biased -> positive). dist[] stores PACKED keys (idx in low 12 mantissa
// bits) -> per-iter tree is 7 v_max_f64, butterfly is update_dpp x2 +
// v_max_f64 per level. Exchange: lane63 ds_write per wave, one barrier, b64
// broadcast read + 3 DPP levels + readfirstlane. out0 written in epilogue.
__global__ __launch_bounds__(512, 2) void fps_kernel(const float* __restrict__ xyz,
                                                     float* __restrict__ out0) {
    const int b = blockIdx.x;
    const int tid = threadIdx.x;
    const int lane = tid & 63, wid = tid >> 6;       // 8 waves
    __shared__ float4 p4[N_];
    __shared__ double candd[2][8];
    const float* xb = xyz + (size_t)b * 3 * N_;

    double x64[8], y64[8], z64[8], q64[8], dist[8];
#pragma unroll
    for (int j = 0; j < 8; ++j) {
        int i = tid + j * 512;
        float x = xb[i], y = xb[N_ + i], z = xb[2 * N_ + i];
        p4[i] = make_float4(x, y, z, 0.f);
        x64[j] = (double)x; y64[j] = (double)y; z64[j] = (double)z;
        q64[j] = x64[j] * x64[j] + y64[j] * y64[j] + z64[j] * z64[j];
        dist[j] = 1e30;
    }
    __syncthreads();

    int far = 0;
    int f0 = 0, f1 = 0;
    for (int s = 0; s < 1023; ++s) {
        float4 c = p4[far];
        f0 = (tid == s) ? far : f0;
        f1 = (tid + 512 == s) ? far : f1;
        double cx = (double)c.x, cy = (double)c.y, cz = (double)c.z;
        double c2p = cx * cx + cy * cy + cz * cz + 1.0;
        double A = -2.0 * cx, Bc = -2.0 * cy, Cc = -2.0 * cz;
#pragma unroll
        for (int j = 0; j < 8; ++j) {
            double d = fma(A, x64[j], fma(Bc, y64[j], fma(Cc, z64[j], q64[j] + c2p)));
            dist[j] = fmin(dist[j], packd(d, tid | (j << 9)));
        }
        double k = fmax(fmax(fmax(dist[0], dist[1]), fmax(dist[2], dist[3])),
                        fmax(fmax(dist[4], dist[5]), fmax(dist[6], dist[7])));
        k = dpp_max_f64<0x111>(k);   // row_shr:1
        k = dpp_max_f64<0x112>(k);   // row_shr:2
        k = dpp_max_f64<0x114>(k);   // row_shr:4
        k = dpp_max_f64<0x118>(k);   // row_shr:8
        k = dpp_max_f64<0x142>(k);   // row_bcast15
        k = dpp_max_f64<0x143>(k);   // row_bcast31
        int buf = s & 1;
        if (lane == 63) candd[buf][wid] = k;
        __syncthreads();
        double k2 = candd[buf][lane & 7];
        k2 = dpp_max_f64<0xB1>(k2);      // quad_perm xor1
        k2 = dpp_max_f64<0x4E>(k2);      // quad_perm xor2
        k2 = dpp_max_f64<0x124>(k2);     // row_ror:4 (8-periodic -> lane0 global)
        unsigned lo = (unsigned)(unsigned long long)__double_as_longlong(k2);
        far = (int)(__builtin_amdgcn_readfirstlane(lo) & 0xFFFu);
    }
    if (tid == 511) f1 = far;
    {
        float4 c0 = p4[f0];
        out0[(size_t)b * 3072 + tid]        = c0.x;
        out0[(size_t)b * 3072 + 1024 + tid] = c0.y;
        out0[(size_t)b * 3072 + 2048 + tid] = c0.z;
        float4 c1 = p4[f1];
        out0[(size_t)b * 3072 + 512 + tid]        = c1.x;
        out0[(size_t)b * 3072 + 1024 + 512 + tid] = c1.y;
        out0[(size_t)b * 3072 + 2048 + 512 + tid] = c1.z;
    }
}

// ---------------------------------------------------------------- prologue: weights->bf16, xyz->double4{x,y,z,|p|^2}
__global__ __launch_bounds__(256) void prep_kernel(const float* __restrict__ xyz,
                                                   const float* __restrict__ W1,
                                                   const float* __restrict__ W2,
                                                   u16* __restrict__ W1bf,
                                                   u16* __restrict__ W2bf,
                                                   double4* __restrict__ xyzq) {
    int t = blockIdx.x * 256 + threadIdx.x;   // grid 256 blocks -> t < 65536
    if (t < 4096) W1bf[t] = f2bf(W1[t]);
    if (t < 8192) W2bf[t] = f2bf(W2[t]);
    int b = t >> 12, i = t & 4095;
    const float* xb = xyz + (size_t)b * 3 * N_;
    // same expressions as the old in-ballq computation -> same contraction ->
    // bit-identical membership decisions
    double x = (double)xb[i], y = (double)xb[N_ + i], z = (double)xb[2 * N_ + i];
    double4 v; v.x = x; v.y = y; v.z = z; v.w = x * x + y * y + z * z;
    xyzq[t] = v;
}

// ---------------------------------------------------------------- ball query
// one wave per centroid; first-32-ascending-index semantics via ballot compaction
__global__ __launch_bounds__(256) void ballq_kernel(const double4* __restrict__ xyzq,
                                                    const float* __restrict__ out0,
                                                    int* __restrict__ idxbuf) {
    int wid = threadIdx.x >> 6, lane = threadIdx.x & 63;
    int m = blockIdx.x * 4 + wid;          // centroid id < 16384
    int b = m >> 10, s = m & 1023;
    const double4* pb = xyzq + (size_t)b * N_;
    double cx = (double)out0[b * 3072 + s];
    double cy = (double)out0[b * 3072 + 1024 + s];
    double cz = (double)out0[b * 3072 + 2048 + s];
    double c2 = cx * cx + cy * cy + cz * cz;
    const double rr = 0.4 * 0.4;
    int* ob = idxbuf + (size_t)m * K_;
    int cnt = 0, first = -1;
    for (int ch = 0; ch < N_ / 64; ++ch) {
        int i = ch * 64 + lane;
        double4 p = pb[i];
        double dot = cx * p.x + cy * p.y + cz * p.z;
        double sqr = (c2 + p.w) - 2.0 * dot;
        bool in = !(sqr > rr);
        unsigned long long mask = __ballot(in);
        if (in) {
            int pos = cnt + __popcll(mask & ((1ull << lane) - 1ull));
            if (pos < K_) ob[pos] = i;
        }
        if (cnt == 0 && mask) first = ch * 64 + (__ffsll((long long)mask) - 1);
        cnt += __popcll(mask);
        if (cnt >= K_) break;
    }
    if (cnt < K_ && lane >= cnt && lane < K_) ob[lane] = first;
}

// ---------------------------------------------------------------- gather + layer0 stats
__global__ __launch_bounds__(256) void gather_stats0(
        const float* __restrict__ xyz, const float* __restrict__ pts,
        const float* __restrict__ out0, const int* __restrict__ idxbuf,
        const float* __restrict__ W0, const float* __restrict__ b0,
        float* __restrict__ F, float2* __restrict__ part) {
    __shared__ float Fs[64][6];
    __shared__ float W0s[384];
    __shared__ float b0s[64];
    __shared__ float2 red[4][64];
    int tid = threadIdx.x;
    long rowbase = (long)blockIdx.x * 64;
    // gather spread across all 256 threads (384 elements, <=2 each)
    for (int e = tid; e < 384; e += 256) {
        int r = e / 6, c = e - r * 6;
        long rw = rowbase + r;
        int b = (int)(rw >> 15);
        int s = ((int)(rw & 32767)) >> 5;
        int i = idxbuf[rw];
        float v;
        if (c < 3)
            v = xyz[(size_t)b * 3 * N_ + c * N_ + i] - out0[b * 3072 + c * 1024 + s];
        else
            v = pts[(size_t)b * 3 * N_ + (c - 3) * N_ + i];
        Fs[r][c] = v;
        F[rw * 6 + c] = v;
    }
    if (tid < 64) b0s[tid] = b0[tid];
    for (int t = tid; t < 384; t += 256) W0s[t] = W0[t];
    __syncthreads();
    int o = tid & 63, rg = tid >> 6;
    float w[6];
#pragma unroll
    for (int c = 0; c < 6; ++c) w[c] = W0s[o * 6 + c];
    float sum = 0.f, sq = 0.f;
#pragma unroll
    for (int rr = 0; rr < 16; ++rr) {
        int rl = rg * 16 + rr;
        float y = b0s[o];
#pragma unroll
        for (int c = 0; c < 6; ++c) y += Fs[rl][c] * w[c];
        sum += y; sq += y * y;
    }
    red[rg][o] = make_float2(sum, sq);
    __syncthreads();
    if (tid < 64) {
        float2 t0 = red[0][tid], t1 = red[1][tid], t2 = red[2][tid], t3 = red[3][tid];
        part[(size_t)blockIdx.x * 64 + tid] =
            make_float2(t0.x + t1.x + t2.x + t3.x, t0.y + t1.y + t2.y + t3.y);
    }
}

// ---------------------------------------------------------------- BN stats reduce
__global__ __launch_bounds__(256) void reduce_stats(const float2* __restrict__ part,
                                                    int nblk, int C,
                                                    const float* __restrict__ g,
                                                    const float* __restrict__ beta,
                                                    float* __restrict__ scale,
                                                    float* __restrict__ shift) {
    int o = blockIdx.x;
    int tid = threadIdx.x;
    double s = 0.0, q = 0.0;
    for (int i = tid; i < nblk; i += 256) {
        float2 v = part[(size_t)i * C + o];
        s += (double)v.x; q += (double)v.y;
    }
    __shared__ double ss[256], qq[256];
    ss[tid] = s; qq[tid] = q;
    __syncthreads();
    for (int m = 128; m > 0; m >>= 1) {
        if (tid < m) { ss[tid] += ss[tid + m]; qq[tid] += qq[tid + m]; }
        __syncthreads();
    }
    if (tid == 0) {
        const double Rd = (double)R_;
        double mean = ss[0] / Rd;
        double var = qq[0] / Rd - mean * mean;
        double sc = (double)g[o] / sqrt(var + 1e-5);
        scale[o] = (float)sc;
        shift[o] = (float)((double)beta[o] - mean * sc);
    }
}

// ---------------------------------------------------------------- layer1: recompute layer0+BN0+relu -> bf16 MFMA GEMM (64x64) -> Y1 bf16 + stats
__global__ __launch_bounds__(256) void layer1_mfma(
        const float* __restrict__ F, const float* __restrict__ W0,
        const float* __restrict__ b0, const float* __restrict__ scale0,
        const float* __restrict__ shift0, const u16* __restrict__ W1bf,
        const float* __restrict__ b1, u16* __restrict__ Y1bf,
        float2* __restrict__ part) {
    __shared__ float Fs[64][6];
    __shared__ float W0s[384];
    __shared__ float b0s[64], sc0[64], sh0[64];
    __shared__ u16 Xs[64][72];
    __shared__ float ssum[16][64];
    __shared__ float ssq[16][64];
    int tid = threadIdx.x;
    long rowbase = (long)blockIdx.x * 64;
    for (int t = tid; t < 384; t += 256) { Fs[t / 6][t % 6] = F[rowbase * 6 + t]; W0s[t] = W0[t]; }
    if (tid < 64) { b0s[tid] = b0[tid]; sc0[tid] = scale0[tid]; sh0[tid] = shift0[tid]; }
    __syncthreads();
    {   // X1 = relu(bn0(F W0^T + b0)) -> bf16 tile
        int o = tid & 63, rg = tid >> 6;
        float w[6];
#pragma unroll
        for (int c = 0; c < 6; ++c) w[c] = W0s[o * 6 + c];
        float sc = sc0[o], sh = sh0[o], bb = b0s[o];
#pragma unroll
        for (int rr = 0; rr < 16; ++rr) {
            int rl = rg * 16 + rr;
            float y = bb;
#pragma unroll
            for (int c = 0; c < 6; ++c) y += Fs[rl][c] * w[c];
            Xs[rl][o] = f2bf(fmaxf(sc * y + sh, 0.f));
        }
    }
    __syncthreads();
    int l = tid & 63, w = tid >> 6;
    int ar = l & 15, kg = l >> 4;     // A row / k-group (also C col / row-group)
    bf16x8 a0 = *(const bf16x8*)&Xs[w * 16 + ar][kg * 8];
    bf16x8 a1 = *(const bf16x8*)&Xs[w * 16 + ar][32 + kg * 8];
    f32x4 acc[4];
#pragma unroll
    for (int t4 = 0; t4 < 4; ++t4) acc[t4] = (f32x4){0.f, 0.f, 0.f, 0.f};
#pragma unroll
    for (int t4 = 0; t4 < 4; ++t4) {
        const u16* wp = &W1bf[(t4 * 16 + ar) * 64 + kg * 8];
        bf16x8 bfr0 = *(const bf16x8*)wp;
        bf16x8 bfr1 = *(const bf16x8*)(wp + 32);
        acc[t4] = __builtin_amdgcn_mfma_f32_16x16x32_bf16(a0, bfr0, acc[t4], 0, 0, 0);
        acc[t4] = __builtin_amdgcn_mfma_f32_16x16x32_bf16(a1, bfr1, acc[t4], 0, 0, 0);
    }
#pragma unroll
    for (int t4 = 0; t4 < 4; ++t4) {
        int col = t4 * 16 + ar;
        float bb = b1[col];
        float s = 0.f, q = 0.f;
#pragma unroll
        for (int r = 0; r < 4; ++r) {
            float y = acc[t4][r] + bb;
            int row = w * 16 + kg * 4 + r;
            Y1bf[(rowbase + row) * 64 + col] = f2bf(y);
            s += y; q += y * y;
        }
        ssum[w * 4 + kg][col] = s;
        ssq[w * 4 + kg][col] = q;
    }
    __syncthreads();
    if (tid < 64) {
        float s = 0.f, q = 0.f;
#pragma unroll
        for (int i = 0; i < 16; ++i) { s += ssum[i][tid]; q += ssq[i][tid]; }
        part[(size_t)blockIdx.x * 64 + tid] = make_float2(s, q);
    }
}

// ---------------------------------------------------------------- layer2: BN1+relu -> bf16 MFMA GEMM (64x128) -> per-sample max/min + stats
__global__ __launch_bounds__(256) void layer2_mfma(
        const u16* __restrict__ Y1bf, const float* __restrict__ scale1,
        const float* __restrict__ shift1, const u16* __restrict__ W2bf,
        const float* __restrict__ b2, float* __restrict__ gmax,
        float* __restrict__ gmin, float2* __restrict__ part) {
    __shared__ u16 Xs[64][72];
    __shared__ float sc1s[64], sh1s[64];
    __shared__ float mxs[16][128], mns[16][128];
    __shared__ float ssum[16][128], ssq[16][128];
    int tid = threadIdx.x;
    long rowbase = (long)blockIdx.x * 64;
    if (tid < 64) { sc1s[tid] = scale1[tid]; sh1s[tid] = shift1[tid]; }
    __syncthreads();
    {   // X2 = relu(bn1(Y1)) -> bf16 tile; vectorized bf16 loads
        int r = tid >> 2, seg = (tid & 3) * 16;
        const u16* yp = &Y1bf[(rowbase + r) * 64 + seg];
        bf16x8 v0 = *(const bf16x8*)yp;
        bf16x8 v1 = *(const bf16x8*)(yp + 8);
#pragma unroll
        for (int j = 0; j < 8; ++j) {
            float x0 = fmaxf(sc1s[seg + j] * bf2f((u16)v0[j]) + sh1s[seg + j], 0.f);
            float x1 = fmaxf(sc1s[seg + 8 + j] * bf2f((u16)v1[j]) + sh1s[seg + 8 + j], 0.f);
            Xs[r][seg + j] = f2bf(x0);
            Xs[r][seg + 8 + j] = f2bf(x1);
        }
    }
    __syncthreads();
    int l = tid & 63, w = tid >> 6;
    int ar = l & 15, kg = l >> 4;
    bf16x8 a0 = *(const bf16x8*)&Xs[w * 16 + ar][kg * 8];
    bf16x8 a1 = *(const bf16x8*)&Xs[w * 16 + ar][32 + kg * 8];
    f32x4 acc[8];
#pragma unroll
    for (int t8 = 0; t8 < 8; ++t8) acc[t8] = (f32x4){0.f, 0.f, 0.f, 0.f};
#pragma unroll
    for (int t8 = 0; t8 < 8; ++t8) {
        const u16* wp = &W2bf[(t8 * 16 + ar) * 64 + kg * 8];
        bf16x8 bfr0 = *(const bf16x8*)wp;
        bf16x8 bfr1 = *(const bf16x8*)(wp + 32);
        acc[t8] = __builtin_amdgcn_mfma_f32_16x16x32_bf16(a0, bfr0, acc[t8], 0, 0, 0);
        acc[t8] = __builtin_amdgcn_mfma_f32_16x16x32_bf16(a1, bfr1, acc[t8], 0, 0, 0);
    }
#pragma unroll
    for (int t8 = 0; t8 < 8; ++t8) {
        int col = t8 * 16 + ar;
        float bb = b2[col];
        float y0 = acc[t8][0] + bb, y1 = acc[t8][1] + bb;
        float y2 = acc[t8][2] + bb, y3 = acc[t8][3] + bb;
        ssum[w * 4 + kg][col] = y0 + y1 + y2 + y3;
        ssq[w * 4 + kg][col] = y0 * y0 + y1 * y1 + y2 * y2 + y3 * y3;
        mxs[w * 4 + kg][col] = fmaxf(fmaxf(y0, y1), fmaxf(y2, y3));
        mns[w * 4 + kg][col] = fminf(fminf(y0, y1), fminf(y2, y3));
    }
    __syncthreads();
    if (tid < 128) {
        int col = tid;
        float s = 0.f, q = 0.f;
        float m0 = -3.0e38f, m1 = -3.0e38f, n0 = 3.0e38f, n1 = 3.0e38f;
#pragma unroll
        for (int i = 0; i < 8; ++i) {
            s += ssum[i][col]; q += ssq[i][col];
            m0 = fmaxf(m0, mxs[i][col]); n0 = fminf(n0, mns[i][col]);
        }
#pragma unroll
        for (int i = 8; i < 16; ++i) {
            s += ssum[i][col]; q += ssq[i][col];
            m1 = fmaxf(m1, mxs[i][col]); n1 = fminf(n1, mns[i][col]);
        }
        part[(size_t)blockIdx.x * 128 + col] = make_float2(s, q);
        gmax[((size_t)blockIdx.x * 2 + 0) * 128 + col] = m0;
        gmax[((size_t)blockIdx.x * 2 + 1) * 128 + col] = m1;
        gmin[((size_t)blockIdx.x * 2 + 0) * 128 + col] = n0;
        gmin[((size_t)blockIdx.x * 2 + 1) * 128 + col] = n1;
    }
}

// ---------------------------------------------------------------- final BN2 + relu + transpose
__global__ __launch_bounds__(256) void final_kernel(const float* __restrict__ gmax,
                                                    const float* __restrict__ gmin,
                                                    const float* __restrict__ scale2,
                                                    const float* __restrict__ shift2,
                                                    float* __restrict__ out1) {
    int b = blockIdx.x, st = blockIdx.y, ot = blockIdx.z;
    __shared__ float tile[32][33];
    int tid = threadIdx.x;
    for (int e = tid; e < 1024; e += 256) {
        int sl = e >> 5, ol = e & 31;
        int s = st * 32 + sl, o = ot * 32 + ol;
        size_t m = (size_t)b * 1024 + s;
        float sc = scale2[o];
        float v = (sc >= 0.f) ? gmax[m * 128 + o] : gmin[m * 128 + o];
        tile[sl][ol] = fmaxf(sc * v + shift2[o], 0.f);
    }
    __syncthreads();
    for (int e = tid; e < 1024; e += 256) {
        int ol = e >> 5, sl = e & 31;
        int s = st * 32 + sl, o = ot * 32 + ol;
        out1[(size_t)b * 131072 + (size_t)o * 1024 + s] = tile[sl][ol];
    }
}

// ---------------------------------------------------------------- launch
extern "C" void kernel_launch(void* const* d_in, const int* in_sizes, int n_in,
                              void* d_out, int out_size, void* d_ws, size_t ws_size,
                              hipStream_t stream) {
    const float* xyz   = (const float*)d_in[0];
    const float* pts   = (const float*)d_in[1];
    const float* W0    = (const float*)d_in[2];
    const float* b0    = (const float*)d_in[3];
    const float* g0    = (const float*)d_in[4];
    const float* beta0 = (const float*)d_in[5];
    const float* W1    = (const float*)d_in[6];
    const float* b1    = (const float*)d_in[7];
    const float* g1    = (const float*)d_in[8];
    const float* beta1 = (const float*)d_in[9];
    const float* W2    = (const float*)d_in[10];
    const float* b2    = (const float*)d_in[11];
    const float* g2    = (const float*)d_in[12];
    const float* beta2 = (const float*)d_in[13];

    float* out0 = (float*)d_out;                  // (B,3,1024)  = 49152
    float* out1 = (float*)d_out + 49152;          // (B,128,1024)

    char* w = (char*)d_ws;
    size_t off = 0;
    double4* xyzq = (double4*)(w + off);  off += (size_t)B_ * N_ * 32;   // 2 MB
    int*    idxbuf = (int*)(w + off);    off += (size_t)R_ * 4;
    float*  F      = (float*)(w + off);  off += (size_t)R_ * 6 * 4;
    u16*    Y1bf   = (u16*)(w + off);    off += (size_t)R_ * 64 * 2;
    float*  gmax   = (float*)(w + off);  off += (size_t)B_ * S_ * 128 * 4;
    float*  gmin   = (float*)(w + off);  off += (size_t)B_ * S_ * 128 * 4;
    float2* part   = (float2*)(w + off); off += (size_t)NBLK_ * 128 * 2 * 4;
    u16*    W1bf   = (u16*)(w + off);    off += 4096 * 2;
    u16*    W2bf   = (u16*)(w + off);    off += 8192 * 2;
    float*  ss     = (float*)(w + off);  off += 512 * 4;
    float* scale0 = ss,       *shift0 = ss + 64;
    float* scale1 = ss + 128, *shift1 = ss + 192;
    float* scale2 = ss + 256, *shift2 = ss + 384;

    prep_kernel<<<256, 256, 0, stream>>>(xyz, W1, W2, W1bf, W2bf, xyzq);
    fps_kernel<<<B_, 512, 0, stream>>>(xyz, out0);
    ballq_kernel<<<(B_ * S_) / 4, 256, 0, stream>>>(xyzq, out0, idxbuf);
    gather_stats0<<<NBLK_, 256, 0, stream>>>(xyz, pts, out0, idxbuf, W0, b0, F, part);
    reduce_stats<<<64, 256, 0, stream>>>(part, NBLK_, 64, g0, beta0, scale0, shift0);
    layer1_mfma<<<NBLK_, 256, 0, stream>>>(F, W0, b0, scale0, shift0, W1bf, b1, Y1bf, part);
    reduce_stats<<<64, 256, 0, stream>>>(part, NBLK_, 64, g1, beta1, scale1, shift1);
    layer2_mfma<<<NBLK_, 256, 0, stream>>>(Y1bf, scale1, shift1, W2bf, b2, gmax, gmin, part);
    reduce_stats<<<128, 256, 0, stream>>>(part, NBLK_, 128, g2, beta2, scale2, shift2);
    final_kernel<<<dim3(B_, 32, 4), 256, 0, stream>>>(gmax, gmin, scale2, shift2, out1);
}

// Round 10
// 813.702 us; speedup vs baseline: 1.2154x; 1.0624x over previous
//
#include <hip/hip_runtime.h>
#include <hip/hip_bf16.h>

#define B_ 16
#define N_ 4096
#define S_ 1024
#define K_ 32
#define R_ (B_*S_*K_)   // 524288 rows
#define NBLK_ (R_/64)   // 8192 row-tiles of 64

typedef unsigned short u16;
typedef __attribute__((ext_vector_type(8))) short bf16x8;
typedef __attribute__((ext_vector_type(4))) float f32x4;

__device__ __forceinline__ u16 f2bf(float f) {
    __hip_bfloat16 h = __float2bfloat16(f);
    return __builtin_bit_cast(u16, h);
}
__device__ __forceinline__ float bf2f(u16 u) {
    unsigned x = ((unsigned)u) << 16;
    return __builtin_bit_cast(float, x);
}

// fmax(v, dpp_move<CTRL>(v)) on f64; identity-preserving (old=own, bound_ctrl=0).
template <int CTRL>
__device__ __forceinline__ double dpp_max_f64(double v) {
    unsigned long long b = (unsigned long long)__double_as_longlong(v);
    int lo = (int)(unsigned)b;
    int hi = (int)(unsigned)(b >> 32);
    int olo = __builtin_amdgcn_update_dpp(lo, lo, CTRL, 0xF, 0xF, false);
    int ohi = __builtin_amdgcn_update_dpp(hi, hi, CTRL, 0xF, 0xF, false);
    double o = __longlong_as_double(
        (long long)(((unsigned long long)(unsigned)ohi << 32) | (unsigned)olo));
    return fmax(v, o);
}

// replace low 12 mantissa bits of positive double with idx (order-preserving key)
__device__ __forceinline__ double packd(double d, int idx) {
    unsigned long long b = (unsigned long long)__double_as_longlong(d);
    b = (b & ~0xFFFull) | (unsigned)idx;
    return __longlong_as_double((long long)b);
}

// ---------------------------------------------------------------- FPS
// r6 structure + centroid-constant LDS table: cd[i] = {-2x, -2y, -2z, |p|^2+1}
// (f64). Centroid fetch = 2 broadcast ds_read_b128 feeding the fma chain
// directly (no cvt / constant-forming chain). Exchange unchanged (r6 measured
// optimum): lane63 ds_write, barrier, b64 broadcast read + 3 DPP + rfl.
__global__ __launch_bounds__(512, 1) void fps_kernel(const float* __restrict__ xyz,
                                                     float* __restrict__ out0) {
    const int b = blockIdx.x;
    const int tid = threadIdx.x;
    const int lane = tid & 63, wid = tid >> 6;       // 8 waves
    __shared__ double4 cd[N_];                       // 128 KB
    __shared__ double candd[2][8];
    const float* xb = xyz + (size_t)b * 3 * N_;

    double x64[8], y64[8], z64[8], q64[8], dist[8];
#pragma unroll
    for (int j = 0; j < 8; ++j) {
        int i = tid + j * 512;
        float x = xb[i], y = xb[N_ + i], z = xb[2 * N_ + i];
        double dx = (double)x, dy = (double)y, dz = (double)z;
        double q = dx * dx + dy * dy + dz * dz;
        double4 v; v.x = -2.0 * dx; v.y = -2.0 * dy; v.z = -2.0 * dz; v.w = q + 1.0;
        cd[i] = v;
        x64[j] = dx; y64[j] = dy; z64[j] = dz; q64[j] = q;
        dist[j] = 1e30;
    }
    __syncthreads();

    int far = 0;
    int f0 = 0, f1 = 0;
    for (int s = 0; s < 1023; ++s) {
        double4 C = cd[far];          // broadcast, 2x ds_read_b128
        f0 = (tid == s) ? far : f0;
        f1 = (tid + 512 == s) ? far : f1;
#pragma unroll
        for (int j = 0; j < 8; ++j) {
            double d = fma(C.x, x64[j], fma(C.y, y64[j], fma(C.z, z64[j], q64[j] + C.w)));
            dist[j] = fmin(dist[j], packd(d, tid | (j << 9)));
        }
        double k = fmax(fmax(fmax(dist[0], dist[1]), fmax(dist[2], dist[3])),
                        fmax(fmax(dist[4], dist[5]), fmax(dist[6], dist[7])));
        k = dpp_max_f64<0x111>(k);   // row_shr:1
        k = dpp_max_f64<0x112>(k);   // row_shr:2
        k = dpp_max_f64<0x114>(k);   // row_shr:4
        k = dpp_max_f64<0x118>(k);   // row_shr:8
        k = dpp_max_f64<0x142>(k);   // row_bcast15
        k = dpp_max_f64<0x143>(k);   // row_bcast31
        int buf = s & 1;
        if (lane == 63) candd[buf][wid] = k;
        __syncthreads();
        double k2 = candd[buf][lane & 7];
        k2 = dpp_max_f64<0xB1>(k2);      // quad_perm xor1
        k2 = dpp_max_f64<0x4E>(k2);      // quad_perm xor2
        k2 = dpp_max_f64<0x124>(k2);     // row_ror:4 (8-periodic -> lane0 global)
        unsigned lo = (unsigned)(unsigned long long)__double_as_longlong(k2);
        far = (int)(__builtin_amdgcn_readfirstlane(lo) & 0xFFFu);
    }
    if (tid == 511) f1 = far;
    {
        // coords recovered exactly: -0.5 * (-2x) == x (power-of-2 muls, bit-exact)
        double4 c0 = cd[f0];
        out0[(size_t)b * 3072 + tid]        = (float)(-0.5 * c0.x);
        out0[(size_t)b * 3072 + 1024 + tid] = (float)(-0.5 * c0.y);
        out0[(size_t)b * 3072 + 2048 + tid] = (float)(-0.5 * c0.z);
        double4 c1 = cd[f1];
        out0[(size_t)b * 3072 + 512 + tid]        = (float)(-0.5 * c1.x);
        out0[(size_t)b * 3072 + 1024 + 512 + tid] = (float)(-0.5 * c1.y);
        out0[(size_t)b * 3072 + 2048 + 512 + tid] = (float)(-0.5 * c1.z);
    }
}

// ---------------------------------------------------------------- prologue: weights->bf16, xyz->double4{x,y,z,|p|^2}
__global__ __launch_bounds__(256) void prep_kernel(const float* __restrict__ xyz,
                                                   const float* __restrict__ W1,
                                                   const float* __restrict__ W2,
                                                   u16* __restrict__ W1bf,
                                                   u16* __restrict__ W2bf,
                                                   double4* __restrict__ xyzq) {
    int t = blockIdx.x * 256 + threadIdx.x;   // grid 256 blocks -> t < 65536
    if (t < 4096) W1bf[t] = f2bf(W1[t]);
    if (t < 8192) W2bf[t] = f2bf(W2[t]);
    int b = t >> 12, i = t & 4095;
    const float* xb = xyz + (size_t)b * 3 * N_;
    double x = (double)xb[i], y = (double)xb[N_ + i], z = (double)xb[2 * N_ + i];
    double4 v; v.x = x; v.y = y; v.z = z; v.w = x * x + y * y + z * z;
    xyzq[t] = v;
}

// ---------------------------------------------------------------- ball query + gather + 27-stat partials
// one wave per centroid (4 centroids = 128 rows per block). ballq exactly as
// before (bit-identical membership), idx mirrored to LDS; lane<32 gathers the
// row's 6 features, writes F, stages the tile; then 216 threads compute the
// block's 27 stats (6 sums + 21 gram entries) over 128 rows.
__global__ __launch_bounds__(256) void ballq_gather(
        const double4* __restrict__ xyzq, const float* __restrict__ out0,
        const float* __restrict__ xyz, const float* __restrict__ pts,
        int* __restrict__ idxbuf, float* __restrict__ F,
        float* __restrict__ part0) {
    __shared__ int idxs[4][32];
    __shared__ float Ftile[128][6];
    __shared__ float red[8][27];
    int wid = threadIdx.x >> 6, lane = threadIdx.x & 63;
    int m = blockIdx.x * 4 + wid;          // centroid id < 16384
    int b = m >> 10, s = m & 1023;
    const double4* pb = xyzq + (size_t)b * N_;
    double cx = (double)out0[b * 3072 + s];
    double cy = (double)out0[b * 3072 + 1024 + s];
    double cz = (double)out0[b * 3072 + 2048 + s];
    double c2 = cx * cx + cy * cy + cz * cz;
    const double rr = 0.4 * 0.4;
    int* ob = idxbuf + (size_t)m * K_;
    int cnt = 0, first = -1;
    for (int ch = 0; ch < N_ / 64; ++ch) {
        int i = ch * 64 + lane;
        double4 p = pb[i];
        double dot = cx * p.x + cy * p.y + cz * p.z;
        double sqr = (c2 + p.w) - 2.0 * dot;
        bool in = !(sqr > rr);
        unsigned long long mask = __ballot(in);
        if (in) {
            int pos = cnt + __popcll(mask & ((1ull << lane) - 1ull));
            if (pos < K_) { ob[pos] = i; idxs[wid][pos] = i; }
        }
        if (cnt == 0 && mask) first = ch * 64 + (__ffsll((long long)mask) - 1);
        cnt += __popcll(mask);
        if (cnt >= K_) break;
    }
    if (cnt < K_ && lane >= cnt && lane < K_) { ob[lane] = first; idxs[wid][lane] = first; }
    __syncthreads();
    if (lane < 32) {
        int i = idxs[wid][lane];
        int rl = wid * 32 + lane;
        long rw = (long)m * 32 + lane;
        float cxf = out0[b * 3072 + s], cyf = out0[b * 3072 + 1024 + s], czf = out0[b * 3072 + 2048 + s];
        const float* xb = xyz + (size_t)b * 3 * N_;
        const float* pp = pts + (size_t)b * 3 * N_;
        float f0v = xb[i] - cxf, f1v = xb[N_ + i] - cyf, f2v = xb[2 * N_ + i] - czf;
        float f3v = pp[i], f4v = pp[N_ + i], f5v = pp[2 * N_ + i];
        Ftile[rl][0] = f0v; Ftile[rl][1] = f1v; Ftile[rl][2] = f2v;
        Ftile[rl][3] = f3v; Ftile[rl][4] = f4v; Ftile[rl][5] = f5v;
        float* Fg = F + rw * 6;
        Fg[0] = f0v; Fg[1] = f1v; Fg[2] = f2v; Fg[3] = f3v; Fg[4] = f4v; Fg[5] = f5v;
    }
    __syncthreads();
    int t = threadIdx.x;
    if (t < 216) {
        const int c1t[27] = {0,1,2,3,4,5, 0,0,0,0,0,0, 1,1,1,1,1, 2,2,2,2, 3,3,3, 4,4, 5};
        const int c2t[27] = {0,1,2,3,4,5, 0,1,2,3,4,5, 1,2,3,4,5, 2,3,4,5, 3,4,5, 4,5, 5};
        int st = t % 27, g = t / 27;
        float acc = 0.f;
        if (st < 6) {
            for (int r = g * 16; r < g * 16 + 16; ++r) acc += Ftile[r][st];
        } else {
            int a = c1t[st], c = c2t[st];
            for (int r = g * 16; r < g * 16 + 16; ++r) acc += Ftile[r][a] * Ftile[r][c];
        }
        red[g][st] = acc;
    }
    __syncthreads();
    if (t < 27) {
        float a = 0.f;
#pragma unroll
        for (int g = 0; g < 8; ++g) a += red[g][t];
        part0[(size_t)blockIdx.x * 27 + t] = a;
    }
}

// ---------------------------------------------------------------- reduce 27 stats over 4096 blocks (f64)
__global__ __launch_bounds__(256) void reduce27(const float* __restrict__ part0,
                                                double* __restrict__ G) {
    int st = blockIdx.x;
    int tid = threadIdx.x;
    double s = 0.0;
    for (int i = tid; i < 4096; i += 256) s += (double)part0[(size_t)i * 27 + st];
    __shared__ double ss[256];
    ss[tid] = s;
    __syncthreads();
    for (int m = 128; m > 0; m >>= 1) {
        if (tid < m) ss[tid] += ss[tid + m];
        __syncthreads();
    }
    if (tid == 0) G[st] = ss[0];
}

// ---------------------------------------------------------------- stats0 from 6-vector + gram (64 threads)
__global__ __launch_bounds__(64) void stats0_final(const double* __restrict__ G,
                                                   const float* __restrict__ W0,
                                                   const float* __restrict__ b0,
                                                   const float* __restrict__ g0,
                                                   const float* __restrict__ beta0,
                                                   float* __restrict__ scale0,
                                                   float* __restrict__ shift0) {
    int o = threadIdx.x;
    double w[6], mvec[6];
#pragma unroll
    for (int c = 0; c < 6; ++c) { w[c] = (double)W0[o * 6 + c]; mvec[c] = G[c]; }
    double dot = 0.0;
#pragma unroll
    for (int c = 0; c < 6; ++c) dot += w[c] * mvec[c];
    const double Rd = (double)R_;
    double bb = (double)b0[o];
    double mu = dot / Rd + bb;
    double quad = 0.0;
    int k = 6;
#pragma unroll
    for (int a = 0; a < 6; ++a)
#pragma unroll
        for (int c = a; c < 6; ++c) {
            double g = G[k++];
            quad += (a == c) ? w[a] * w[c] * g : 2.0 * w[a] * w[c] * g;
        }
    double ey2 = (quad + 2.0 * bb * dot) / Rd + bb * bb;
    double var = ey2 - mu * mu;
    double sc = (double)g0[o] / sqrt(var + 1e-5);
    scale0[o] = (float)sc;
    shift0[o] = (float)((double)beta0[o] - mu * sc);
}

// ---------------------------------------------------------------- BN stats reduce (layers 1,2)
__global__ __launch_bounds__(256) void reduce_stats(const float2* __restrict__ part,
                                                    int nblk, int C,
                                                    const float* __restrict__ g,
                                                    const float* __restrict__ beta,
                                                    float* __restrict__ scale,
                                                    float* __restrict__ shift) {
    int o = blockIdx.x;
    int tid = threadIdx.x;
    double s = 0.0, q = 0.0;
    for (int i = tid; i < nblk; i += 256) {
        float2 v = part[(size_t)i * C + o];
        s += (double)v.x; q += (double)v.y;
    }
    __shared__ double ss[256], qq[256];
    ss[tid] = s; qq[tid] = q;
    __syncthreads();
    for (int m = 128; m > 0; m >>= 1) {
        if (tid < m) { ss[tid] += ss[tid + m]; qq[tid] += qq[tid + m]; }
        __syncthreads();
    }
    if (tid == 0) {
        const double Rd = (double)R_;
        double mean = ss[0] / Rd;
        double var = qq[0] / Rd - mean * mean;
        double sc = (double)g[o] / sqrt(var + 1e-5);
        scale[o] = (float)sc;
        shift[o] = (float)((double)beta[o] - mean * sc);
    }
}

// ---------------------------------------------------------------- layer1: recompute layer0+BN0+relu -> bf16 MFMA GEMM (64x64) -> Y1 bf16 + stats
__global__ __launch_bounds__(256) void layer1_mfma(
        const float* __restrict__ F, const float* __restrict__ W0,
        const float* __restrict__ b0, const float* __restrict__ scale0,
        const float* __restrict__ shift0, const u16* __restrict__ W1bf,
        const float* __restrict__ b1, u16* __restrict__ Y1bf,
        float2* __restrict__ part) {
    __shared__ float Fs[64][6];
    __shared__ float W0s[384];
    __shared__ float b0s[64], sc0[64], sh0[64];
    __shared__ u16 Xs[64][72];
    __shared__ float ssum[16][64];
    __shared__ float ssq[16][64];
    int tid = threadIdx.x;
    long rowbase = (long)blockIdx.x * 64;
    for (int t = tid; t < 384; t += 256) { Fs[t / 6][t % 6] = F[rowbase * 6 + t]; W0s[t] = W0[t]; }
    if (tid < 64) { b0s[tid] = b0[tid]; sc0[tid] = scale0[tid]; sh0[tid] = shift0[tid]; }
    __syncthreads();
    {   // X1 = relu(bn0(F W0^T + b0)) -> bf16 tile
        int o = tid & 63, rg = tid >> 6;
        float w[6];
#pragma unroll
        for (int c = 0; c < 6; ++c) w[c] = W0s[o * 6 + c];
        float sc = sc0[o], sh = sh0[o], bb = b0s[o];
#pragma unroll
        for (int rr = 0; rr < 16; ++rr) {
            int rl = rg * 16 + rr;
            float y = bb;
#pragma unroll
            for (int c = 0; c < 6; ++c) y += Fs[rl][c] * w[c];
            Xs[rl][o] = f2bf(fmaxf(sc * y + sh, 0.f));
        }
    }
    __syncthreads();
    int l = tid & 63, w = tid >> 6;
    int ar = l & 15, kg = l >> 4;     // A row / k-group (also C col / row-group)
    bf16x8 a0 = *(const bf16x8*)&Xs[w * 16 + ar][kg * 8];
    bf16x8 a1 = *(const bf16x8*)&Xs[w * 16 + ar][32 + kg * 8];
    f32x4 acc[4];
#pragma unroll
    for (int t4 = 0; t4 < 4; ++t4) acc[t4] = (f32x4){0.f, 0.f, 0.f, 0.f};
#pragma unroll
    for (int t4 = 0; t4 < 4; ++t4) {
        const u16* wp = &W1bf[(t4 * 16 + ar) * 64 + kg * 8];
        bf16x8 bfr0 = *(const bf16x8*)wp;
        bf16x8 bfr1 = *(const bf16x8*)(wp + 32);
        acc[t4] = __builtin_amdgcn_mfma_f32_16x16x32_bf16(a0, bfr0, acc[t4], 0, 0, 0);
        acc[t4] = __builtin_amdgcn_mfma_f32_16x16x32_bf16(a1, bfr1, acc[t4], 0, 0, 0);
    }
#pragma unroll
    for (int t4 = 0; t4 < 4; ++t4) {
        int col = t4 * 16 + ar;
        float bb = b1[col];
        float s = 0.f, q = 0.f;
#pragma unroll
        for (int r = 0; r < 4; ++r) {
            float y = acc[t4][r] + bb;
            int row = w * 16 + kg * 4 + r;
            Y1bf[(rowbase + row) * 64 + col] = f2bf(y);
            s += y; q += y * y;
        }
        ssum[w * 4 + kg][col] = s;
        ssq[w * 4 + kg][col] = q;
    }
    __syncthreads();
    if (tid < 64) {
        float s = 0.f, q = 0.f;
#pragma unroll
        for (int i = 0; i < 16; ++i) { s += ssum[i][tid]; q += ssq[i][tid]; }
        part[(size_t)blockIdx.x * 64 + tid] = make_float2(s, q);
    }
}

// ---------------------------------------------------------------- layer2: BN1+relu -> bf16 MFMA GEMM (64x128) -> per-sample max/min + stats
__global__ __launch_bounds__(256) void layer2_mfma(
        const u16* __restrict__ Y1bf, const float* __restrict__ scale1,
        const float* __restrict__ shift1, const u16* __restrict__ W2bf,
        const float* __restrict__ b2, float* __restrict__ gmax,
        float* __restrict__ gmin, float2* __restrict__ part) {
    __shared__ u16 Xs[64][72];
    __shared__ float sc1s[64], sh1s[64];
    __shared__ float mxs[16][128], mns[16][128];
    __shared__ float ssum[16][128], ssq[16][128];
    int tid = threadIdx.x;
    long rowbase = (long)blockIdx.x * 64;
    if (tid < 64) { sc1s[tid] = scale1[tid]; sh1s[tid] = shift1[tid]; }
    __syncthreads();
    {   // X2 = relu(bn1(Y1)) -> bf16 tile; vectorized bf16 loads
        int r = tid >> 2, seg = (tid & 3) * 16;
        const u16* yp = &Y1bf[(rowbase + r) * 64 + seg];
        bf16x8 v0 = *(const bf16x8*)yp;
        bf16x8 v1 = *(const bf16x8*)(yp + 8);
#pragma unroll
        for (int j = 0; j < 8; ++j) {
            float x0 = fmaxf(sc1s[seg + j] * bf2f((u16)v0[j]) + sh1s[seg + j], 0.f);
            float x1 = fmaxf(sc1s[seg + 8 + j] * bf2f((u16)v1[j]) + sh1s[seg + 8 + j], 0.f);
            Xs[r][seg + j] = f2bf(x0);
            Xs[r][seg + 8 + j] = f2bf(x1);
        }
    }
    __syncthreads();
    int l = tid & 63, w = tid >> 6;
    int ar = l & 15, kg = l >> 4;
    bf16x8 a0 = *(const bf16x8*)&Xs[w * 16 + ar][kg * 8];
    bf16x8 a1 = *(const bf16x8*)&Xs[w * 16 + ar][32 + kg * 8];
    f32x4 acc[8];
#pragma unroll
    for (int t8 = 0; t8 < 8; ++t8) acc[t8] = (f32x4){0.f, 0.f, 0.f, 0.f};
#pragma unroll
    for (int t8 = 0; t8 < 8; ++t8) {
        const u16* wp = &W2bf[(t8 * 16 + ar) * 64 + kg * 8];
        bf16x8 bfr0 = *(const bf16x8*)wp;
        bf16x8 bfr1 = *(const bf16x8*)(wp + 32);
        acc[t8] = __builtin_amdgcn_mfma_f32_16x16x32_bf16(a0, bfr0, acc[t8], 0, 0, 0);
        acc[t8] = __builtin_amdgcn_mfma_f32_16x16x32_bf16(a1, bfr1, acc[t8], 0, 0, 0);
    }
#pragma unroll
    for (int t8 = 0; t8 < 8; ++t8) {
        int col = t8 * 16 + ar;
        float bb = b2[col];
        float y0 = acc[t8][0] + bb, y1 = acc[t8][1] + bb;
        float y2 = acc[t8][2] + bb, y3 = acc[t8][3] + bb;
        ssum[w * 4 + kg][col] = y0 + y1 + y2 + y3;
        ssq[w * 4 + kg][col] = y0 * y0 + y1 * y1 + y2 * y2 + y3 * y3;
        mxs[w * 4 + kg][col] = fmaxf(fmaxf(y0, y1), fmaxf(y2, y3));
        mns[w * 4 + kg][col] = fminf(fminf(y0, y1), fminf(y2, y3));
    }
    __syncthreads();
    if (tid < 128) {
        int col = tid;
        float s = 0.f, q = 0.f;
        float m0 = -3.0e38f, m1 = -3.0e38f, n0 = 3.0e38f, n1 = 3.0e38f;
#pragma unroll
        for (int i = 0; i < 8; ++i) {
            s += ssum[i][col]; q += ssq[i][col];
            m0 = fmaxf(m0, mxs[i][col]); n0 = fminf(n0, mns[i][col]);
        }
#pragma unroll
        for (int i = 8; i < 16; ++i) {
            s += ssum[i][col]; q += ssq[i][col];
            m1 = fmaxf(m1, mxs[i][col]); n1 = fminf(n1, mns[i][col]);
        }
        part[(size_t)blockIdx.x * 128 + col] = make_float2(s, q);
        gmax[((size_t)blockIdx.x * 2 + 0) * 128 + col] = m0;
        gmax[((size_t)blockIdx.x * 2 + 1) * 128 + col] = m1;
        gmin[((size_t)blockIdx.x * 2 + 0) * 128 + col] = n0;
        gmin[((size_t)blockIdx.x * 2 + 1) * 128 + col] = n1;
    }
}

// ---------------------------------------------------------------- final BN2 + relu + transpose
__global__ __launch_bounds__(256) void final_kernel(const float* __restrict__ gmax,
                                                    const float* __restrict__ gmin,
                                                    const float* __restrict__ scale2,
                                                    const float* __restrict__ shift2,
                                                    float* __restrict__ out1) {
    int b = blockIdx.x, st = blockIdx.y, ot = blockIdx.z;
    __shared__ float tile[32][33];
    int tid = threadIdx.x;
    for (int e = tid; e < 1024; e += 256) {
        int sl = e >> 5, ol = e & 31;
        int s = st * 32 + sl, o = ot * 32 + ol;
        size_t m = (size_t)b * 1024 + s;
        float sc = scale2[o];
        float v = (sc >= 0.f) ? gmax[m * 128 + o] : gmin[m * 128 + o];
        tile[sl][ol] = fmaxf(sc * v + shift2[o], 0.f);
    }
    __syncthreads();
    for (int e = tid; e < 1024; e += 256) {
        int ol = e >> 5, sl = e & 31;
        int s = st * 32 + sl, o = ot * 32 + ol;
        out1[(size_t)b * 131072 + (size_t)o * 1024 + s] = tile[sl][ol];
    }
}

// ---------------------------------------------------------------- launch
extern "C" void kernel_launch(void* const* d_in, const int* in_sizes, int n_in,
                              void* d_out, int out_size, void* d_ws, size_t ws_size,
                              hipStream_t stream) {
    const float* xyz   = (const float*)d_in[0];
    const float* pts   = (const float*)d_in[1];
    const float* W0    = (const float*)d_in[2];
    const float* b0    = (const float*)d_in[3];
    const float* g0    = (const float*)d_in[4];
    const float* beta0 = (const float*)d_in[5];
    const float* W1    = (const float*)d_in[6];
    const float* b1    = (const float*)d_in[7];
    const float* g1    = (const float*)d_in[8];
    const float* beta1 = (const float*)d_in[9];
    const float* W2    = (const float*)d_in[10];
    const float* b2    = (const float*)d_in[11];
    const float* g2    = (const float*)d_in[12];
    const float* beta2 = (const float*)d_in[13];

    float* out0 = (float*)d_out;                  // (B,3,1024)  = 49152
    float* out1 = (float*)d_out + 49152;          // (B,128,1024)

    char* w = (char*)d_ws;
    size_t off = 0;
    double4* xyzq = (double4*)(w + off);  off += (size_t)B_ * N_ * 32;   // 2 MB
    int*    idxbuf = (int*)(w + off);    off += (size_t)R_ * 4;
    float*  F      = (float*)(w + off);  off += (size_t)R_ * 6 * 4;
    u16*    Y1bf   = (u16*)(w + off);    off += (size_t)R_ * 64 * 2;
    float*  gmax   = (float*)(w + off);  off += (size_t)B_ * S_ * 128 * 4;
    float*  gmin   = (float*)(w + off);  off += (size_t)B_ * S_ * 128 * 4;
    float2* part   = (float2*)(w + off); off += (size_t)NBLK_ * 128 * 2 * 4;
    float*  part0  = (float*)(w + off);  off += (size_t)4096 * 27 * 4;
    double* G27    = (double*)(w + off); off += 32 * 8;
    u16*    W1bf   = (u16*)(w + off);    off += 4096 * 2;
    u16*    W2bf   = (u16*)(w + off);    off += 8192 * 2;
    float*  ss     = (float*)(w + off);  off += 512 * 4;
    float* scale0 = ss,       *shift0 = ss + 64;
    float* scale1 = ss + 128, *shift1 = ss + 192;
    float* scale2 = ss + 256, *shift2 = ss + 384;

    prep_kernel<<<256, 256, 0, stream>>>(xyz, W1, W2, W1bf, W2bf, xyzq);
    fps_kernel<<<B_, 512, 0, stream>>>(xyz, out0);
    ballq_gather<<<(B_ * S_) / 4, 256, 0, stream>>>(xyzq, out0, xyz, pts, idxbuf, F, part0);
    reduce27<<<27, 256, 0, stream>>>(part0, G27);
    stats0_final<<<1, 64, 0, stream>>>(G27, W0, b0, g0, beta0, scale0, shift0);
    layer1_mfma<<<NBLK_, 256, 0, stream>>>(F, W0, b0, scale0, shift0, W1bf, b1, Y1bf, part);
    reduce_stats<<<64, 256, 0, stream>>>(part, NBLK_, 64, g1, beta1, scale1, shift1);
    layer2_mfma<<<NBLK_, 256, 0, stream>>>(Y1bf, scale1, shift1, W2bf, b2, gmax, gmin, part);
    reduce_stats<<<128, 256, 0, stream>>>(part, NBLK_, 128, g2, beta2, scale2, shift2);
    final_kernel<<<dim3(B_, 32, 4), 256, 0, stream>>>(gmax, gmin, scale2, shift2, out1);
}

// Round 11
// 794.146 us; speedup vs baseline: 1.2454x; 1.0246x over previous
//
#include <hip/hip_runtime.h>
#include <hip/hip_bf16.h>

#define B_ 16
#define N_ 4096
#define S_ 1024
#define K_ 32
#define R_ (B_*S_*K_)   // 524288 rows
#define NB1_ (R_/128)   // 4096 row-tiles of 128

typedef unsigned short u16;
typedef __attribute__((ext_vector_type(8))) short bf16x8;
typedef __attribute__((ext_vector_type(4))) float f32x4;

__device__ __forceinline__ u16 f2bf(float f) {
    __hip_bfloat16 h = __float2bfloat16(f);
    return __builtin_bit_cast(u16, h);
}
__device__ __forceinline__ float bf2f(u16 u) {
    unsigned x = ((unsigned)u) << 16;
    return __builtin_bit_cast(float, x);
}

// fmax(v, dpp_move<CTRL>(v)) on f64; identity-preserving (old=own, bound_ctrl=0).
template <int CTRL>
__device__ __forceinline__ double dpp_max_f64(double v) {
    unsigned long long b = (unsigned long long)__double_as_longlong(v);
    int lo = (int)(unsigned)b;
    int hi = (int)(unsigned)(b >> 32);
    int olo = __builtin_amdgcn_update_dpp(lo, lo, CTRL, 0xF, 0xF, false);
    int ohi = __builtin_amdgcn_update_dpp(hi, hi, CTRL, 0xF, 0xF, false);
    double o = __longlong_as_double(
        (long long)(((unsigned long long)(unsigned)ohi << 32) | (unsigned)olo));
    return fmax(v, o);
}

// replace low 12 mantissa bits of positive double with idx (order-preserving key)
__device__ __forceinline__ double packd(double d, int idx) {
    unsigned long long b = (unsigned long long)__double_as_longlong(d);
    b = (b & ~0xFFFull) | (unsigned)idx;
    return __longlong_as_double((long long)b);
}

// ---------------------------------------------------------------- FPS (r10 measured optimum — unchanged)
__global__ __launch_bounds__(512, 1) void fps_kernel(const float* __restrict__ xyz,
                                                     float* __restrict__ out0) {
    const int b = blockIdx.x;
    const int tid = threadIdx.x;
    const int lane = tid & 63, wid = tid >> 6;       // 8 waves
    __shared__ double4 cd[N_];                       // 128 KB
    __shared__ double candd[2][8];
    const float* xb = xyz + (size_t)b * 3 * N_;

    double x64[8], y64[8], z64[8], q64[8], dist[8];
#pragma unroll
    for (int j = 0; j < 8; ++j) {
        int i = tid + j * 512;
        float x = xb[i], y = xb[N_ + i], z = xb[2 * N_ + i];
        double dx = (double)x, dy = (double)y, dz = (double)z;
        double q = dx * dx + dy * dy + dz * dz;
        double4 v; v.x = -2.0 * dx; v.y = -2.0 * dy; v.z = -2.0 * dz; v.w = q + 1.0;
        cd[i] = v;
        x64[j] = dx; y64[j] = dy; z64[j] = dz; q64[j] = q;
        dist[j] = 1e30;
    }
    __syncthreads();

    int far = 0;
    int f0 = 0, f1 = 0;
    for (int s = 0; s < 1023; ++s) {
        double4 C = cd[far];          // broadcast, 2x ds_read_b128
        f0 = (tid == s) ? far : f0;
        f1 = (tid + 512 == s) ? far : f1;
#pragma unroll
        for (int j = 0; j < 8; ++j) {
            double d = fma(C.x, x64[j], fma(C.y, y64[j], fma(C.z, z64[j], q64[j] + C.w)));
            dist[j] = fmin(dist[j], packd(d, tid | (j << 9)));
        }
        double k = fmax(fmax(fmax(dist[0], dist[1]), fmax(dist[2], dist[3])),
                        fmax(fmax(dist[4], dist[5]), fmax(dist[6], dist[7])));
        k = dpp_max_f64<0x111>(k);   // row_shr:1
        k = dpp_max_f64<0x112>(k);   // row_shr:2
        k = dpp_max_f64<0x114>(k);   // row_shr:4
        k = dpp_max_f64<0x118>(k);   // row_shr:8
        k = dpp_max_f64<0x142>(k);   // row_bcast15
        k = dpp_max_f64<0x143>(k);   // row_bcast31
        int buf = s & 1;
        if (lane == 63) candd[buf][wid] = k;
        __syncthreads();
        double k2 = candd[buf][lane & 7];
        k2 = dpp_max_f64<0xB1>(k2);      // quad_perm xor1
        k2 = dpp_max_f64<0x4E>(k2);      // quad_perm xor2
        k2 = dpp_max_f64<0x124>(k2);     // row_ror:4 (8-periodic -> lane0 global)
        unsigned lo = (unsigned)(unsigned long long)__double_as_longlong(k2);
        far = (int)(__builtin_amdgcn_readfirstlane(lo) & 0xFFFu);
    }
    if (tid == 511) f1 = far;
    {
        // coords recovered exactly: -0.5 * (-2x) == x (power-of-2 muls, bit-exact)
        double4 c0 = cd[f0];
        out0[(size_t)b * 3072 + tid]        = (float)(-0.5 * c0.x);
        out0[(size_t)b * 3072 + 1024 + tid] = (float)(-0.5 * c0.y);
        out0[(size_t)b * 3072 + 2048 + tid] = (float)(-0.5 * c0.z);
        double4 c1 = cd[f1];
        out0[(size_t)b * 3072 + 512 + tid]        = (float)(-0.5 * c1.x);
        out0[(size_t)b * 3072 + 1024 + 512 + tid] = (float)(-0.5 * c1.y);
        out0[(size_t)b * 3072 + 2048 + 512 + tid] = (float)(-0.5 * c1.z);
    }
}

// ---------------------------------------------------------------- prologue: weights->bf16, xyz->double4{x,y,z,|p|^2}
__global__ __launch_bounds__(256) void prep_kernel(const float* __restrict__ xyz,
                                                   const float* __restrict__ W1,
                                                   const float* __restrict__ W2,
                                                   u16* __restrict__ W1bf,
                                                   u16* __restrict__ W2bf,
                                                   double4* __restrict__ xyzq) {
    int t = blockIdx.x * 256 + threadIdx.x;   // grid 256 blocks -> t < 65536
    if (t < 4096) W1bf[t] = f2bf(W1[t]);
    if (t < 8192) W2bf[t] = f2bf(W2[t]);
    int b = t >> 12, i = t & 4095;
    const float* xb = xyz + (size_t)b * 3 * N_;
    double x = (double)xb[i], y = (double)xb[N_ + i], z = (double)xb[2 * N_ + i];
    double4 v; v.x = x; v.y = y; v.z = z; v.w = x * x + y * y + z * z;
    xyzq[t] = v;
}

// ---------------------------------------------------------------- ball query + gather + 27-stat partials
// one wave per centroid (4 centroids = 128 rows per block). ballq bit-identical
// to reference semantics; gather uses all 64 lanes (lo half: xyz-diff, hi
// half: pts). 216 threads then compute 27 stats (6 sums + 21 gram) per block.
__global__ __launch_bounds__(256) void ballq_gather(
        const double4* __restrict__ xyzq, const float* __restrict__ out0,
        const float* __restrict__ xyz, const float* __restrict__ pts,
        int* __restrict__ idxbuf, float* __restrict__ F,
        float* __restrict__ part0) {
    __shared__ int idxs[4][32];
    __shared__ float Ftile[128][6];
    __shared__ float red[8][27];
    int wid = threadIdx.x >> 6, lane = threadIdx.x & 63;
    int m = blockIdx.x * 4 + wid;          // centroid id < 16384
    int b = m >> 10, s = m & 1023;
    const double4* pb = xyzq + (size_t)b * N_;
    double cx = (double)out0[b * 3072 + s];
    double cy = (double)out0[b * 3072 + 1024 + s];
    double cz = (double)out0[b * 3072 + 2048 + s];
    double c2 = cx * cx + cy * cy + cz * cz;
    const double rr = 0.4 * 0.4;
    int* ob = idxbuf + (size_t)m * K_;
    int cnt = 0, first = -1;
    for (int ch = 0; ch < N_ / 64; ++ch) {
        int i = ch * 64 + lane;
        double4 p = pb[i];
        double dot = cx * p.x + cy * p.y + cz * p.z;
        double sqr = (c2 + p.w) - 2.0 * dot;
        bool in = !(sqr > rr);
        unsigned long long mask = __ballot(in);
        if (in) {
            int pos = cnt + __popcll(mask & ((1ull << lane) - 1ull));
            if (pos < K_) { ob[pos] = i; idxs[wid][pos] = i; }
        }
        if (cnt == 0 && mask) first = ch * 64 + (__ffsll((long long)mask) - 1);
        cnt += __popcll(mask);
        if (cnt >= K_) break;
    }
    if (cnt < K_ && lane >= cnt && lane < K_) { ob[lane] = first; idxs[wid][lane] = first; }
    __syncthreads();
    {
        int l2 = lane & 31;
        int i = idxs[wid][l2];
        int rl = wid * 32 + l2;
        long rw = (long)m * 32 + l2;
        float* Fg = F + rw * 6;
        if (lane < 32) {
            float cxf = out0[b * 3072 + s], cyf = out0[b * 3072 + 1024 + s],
                  czf = out0[b * 3072 + 2048 + s];
            const float* xb = xyz + (size_t)b * 3 * N_;
            float f0v = xb[i] - cxf, f1v = xb[N_ + i] - cyf, f2v = xb[2 * N_ + i] - czf;
            Ftile[rl][0] = f0v; Ftile[rl][1] = f1v; Ftile[rl][2] = f2v;
            Fg[0] = f0v; Fg[1] = f1v; Fg[2] = f2v;
        } else {
            const float* pp = pts + (size_t)b * 3 * N_;
            float f3v = pp[i], f4v = pp[N_ + i], f5v = pp[2 * N_ + i];
            Ftile[rl][3] = f3v; Ftile[rl][4] = f4v; Ftile[rl][5] = f5v;
            Fg[3] = f3v; Fg[4] = f4v; Fg[5] = f5v;
        }
    }
    __syncthreads();
    int t = threadIdx.x;
    if (t < 216) {
        const int c1t[27] = {0,1,2,3,4,5, 0,0,0,0,0,0, 1,1,1,1,1, 2,2,2,2, 3,3,3, 4,4, 5};
        const int c2t[27] = {0,1,2,3,4,5, 0,1,2,3,4,5, 1,2,3,4,5, 2,3,4,5, 3,4,5, 4,5, 5};
        int st = t % 27, g = t / 27;
        float acc = 0.f;
        if (st < 6) {
            for (int r = g * 16; r < g * 16 + 16; ++r) acc += Ftile[r][st];
        } else {
            int a = c1t[st], c = c2t[st];
            for (int r = g * 16; r < g * 16 + 16; ++r) acc += Ftile[r][a] * Ftile[r][c];
        }
        red[g][st] = acc;
    }
    __syncthreads();
    if (t < 27) {
        float a = 0.f;
#pragma unroll
        for (int g = 0; g < 8; ++g) a += red[g][t];
        part0[(size_t)blockIdx.x * 27 + t] = a;
    }
}

// ---------------------------------------------------------------- reduce 27 stats over 4096 blocks (f64)
__global__ __launch_bounds__(256) void reduce27(const float* __restrict__ part0,
                                                double* __restrict__ G) {
    int st = blockIdx.x;
    int tid = threadIdx.x;
    double s = 0.0;
    for (int i = tid; i < 4096; i += 256) s += (double)part0[(size_t)i * 27 + st];
    __shared__ double ss[256];
    ss[tid] = s;
    __syncthreads();
    for (int m = 128; m > 0; m >>= 1) {
        if (tid < m) ss[tid] += ss[tid + m];
        __syncthreads();
    }
    if (tid == 0) G[st] = ss[0];
}

// ---------------------------------------------------------------- stats0 from 6-vector + gram (64 threads)
__global__ __launch_bounds__(64) void stats0_final(const double* __restrict__ G,
                                                   const float* __restrict__ W0,
                                                   const float* __restrict__ b0,
                                                   const float* __restrict__ g0,
                                                   const float* __restrict__ beta0,
                                                   float* __restrict__ scale0,
                                                   float* __restrict__ shift0) {
    int o = threadIdx.x;
    double w[6], mvec[6];
#pragma unroll
    for (int c = 0; c < 6; ++c) { w[c] = (double)W0[o * 6 + c]; mvec[c] = G[c]; }
    double dot = 0.0;
#pragma unroll
    for (int c = 0; c < 6; ++c) dot += w[c] * mvec[c];
    const double Rd = (double)R_;
    double bb = (double)b0[o];
    double mu = dot / Rd + bb;
    double quad = 0.0;
    int k = 6;
#pragma unroll
    for (int a = 0; a < 6; ++a)
#pragma unroll
        for (int c = a; c < 6; ++c) {
            double g = G[k++];
            quad += (a == c) ? w[a] * w[c] * g : 2.0 * w[a] * w[c] * g;
        }
    double ey2 = (quad + 2.0 * bb * dot) / Rd + bb * bb;
    double var = ey2 - mu * mu;
    double sc = (double)g0[o] / sqrt(var + 1e-5);
    scale0[o] = (float)sc;
    shift0[o] = (float)((double)beta0[o] - mu * sc);
}

// ---------------------------------------------------------------- BN stats reduce (layers 1,2)
__global__ __launch_bounds__(256) void reduce_stats(const float2* __restrict__ part,
                                                    int nblk, int C,
                                                    const float* __restrict__ g,
                                                    const float* __restrict__ beta,
                                                    float* __restrict__ scale,
                                                    float* __restrict__ shift) {
    int o = blockIdx.x;
    int tid = threadIdx.x;
    double s = 0.0, q = 0.0;
    for (int i = tid; i < nblk; i += 256) {
        float2 v = part[(size_t)i * C + o];
        s += (double)v.x; q += (double)v.y;
    }
    __shared__ double ss[256], qq[256];
    ss[tid] = s; qq[tid] = q;
    __syncthreads();
    for (int m = 128; m > 0; m >>= 1) {
        if (tid < m) { ss[tid] += ss[tid + m]; qq[tid] += qq[tid + m]; }
        __syncthreads();
    }
    if (tid == 0) {
        const double Rd = (double)R_;
        double mean = ss[0] / Rd;
        double var = qq[0] / Rd - mean * mean;
        double sc = (double)g[o] / sqrt(var + 1e-5);
        scale[o] = (float)sc;
        shift[o] = (float)((double)beta[o] - mean * sc);
    }
}

// ---------------------------------------------------------------- layer1: 128-row tile, 512 threads
__global__ __launch_bounds__(512) void layer1_mfma(
        const float* __restrict__ F, const float* __restrict__ W0,
        const float* __restrict__ b0, const float* __restrict__ scale0,
        const float* __restrict__ shift0, const u16* __restrict__ W1bf,
        const float* __restrict__ b1, u16* __restrict__ Y1bf,
        float2* __restrict__ part) {
    __shared__ float Fs[128][6];
    __shared__ float W0s[384];
    __shared__ float b0s[64], sc0[64], sh0[64];
    __shared__ u16 Xs[128][72];
    __shared__ float ssum[32][64];
    __shared__ float ssq[32][64];
    int tid = threadIdx.x;
    long rowbase = (long)blockIdx.x * 128;
    for (int t = tid; t < 768; t += 512) Fs[t / 6][t % 6] = F[rowbase * 6 + t];
    if (tid < 384) W0s[tid] = W0[tid];
    if (tid < 64) { b0s[tid] = b0[tid]; sc0[tid] = scale0[tid]; sh0[tid] = shift0[tid]; }
    __syncthreads();
    {   // X1 = relu(bn0(F W0^T + b0)) -> bf16 tile
        int o = tid & 63, rg = tid >> 6;           // 8 row-groups x 16 rows
        float w[6];
#pragma unroll
        for (int c = 0; c < 6; ++c) w[c] = W0s[o * 6 + c];
        float sc = sc0[o], sh = sh0[o], bb = b0s[o];
#pragma unroll
        for (int rr = 0; rr < 16; ++rr) {
            int rl = rg * 16 + rr;
            float y = bb;
#pragma unroll
            for (int c = 0; c < 6; ++c) y += Fs[rl][c] * w[c];
            Xs[rl][o] = f2bf(fmaxf(sc * y + sh, 0.f));
        }
    }
    __syncthreads();
    int l = tid & 63, w = tid >> 6;                // 8 waves x 16 rows
    int ar = l & 15, kg = l >> 4;
    bf16x8 a0 = *(const bf16x8*)&Xs[w * 16 + ar][kg * 8];
    bf16x8 a1 = *(const bf16x8*)&Xs[w * 16 + ar][32 + kg * 8];
    f32x4 acc[4];
#pragma unroll
    for (int t4 = 0; t4 < 4; ++t4) acc[t4] = (f32x4){0.f, 0.f, 0.f, 0.f};
#pragma unroll
    for (int t4 = 0; t4 < 4; ++t4) {
        const u16* wp = &W1bf[(t4 * 16 + ar) * 64 + kg * 8];
        bf16x8 bfr0 = *(const bf16x8*)wp;
        bf16x8 bfr1 = *(const bf16x8*)(wp + 32);
        acc[t4] = __builtin_amdgcn_mfma_f32_16x16x32_bf16(a0, bfr0, acc[t4], 0, 0, 0);
        acc[t4] = __builtin_amdgcn_mfma_f32_16x16x32_bf16(a1, bfr1, acc[t4], 0, 0, 0);
    }
#pragma unroll
    for (int t4 = 0; t4 < 4; ++t4) {
        int col = t4 * 16 + ar;
        float bb = b1[col];
        float s = 0.f, q = 0.f;
#pragma unroll
        for (int r = 0; r < 4; ++r) {
            float y = acc[t4][r] + bb;
            int row = w * 16 + kg * 4 + r;
            Y1bf[(rowbase + row) * 64 + col] = f2bf(y);
            s += y; q += y * y;
        }
        ssum[w * 4 + kg][col] = s;
        ssq[w * 4 + kg][col] = q;
    }
    __syncthreads();
    if (tid < 64) {
        float s = 0.f, q = 0.f;
#pragma unroll
        for (int i = 0; i < 32; ++i) { s += ssum[i][tid]; q += ssq[i][tid]; }
        part[(size_t)blockIdx.x * 64 + tid] = make_float2(s, q);
    }
}

// ---------------------------------------------------------------- layer2: 128-row tile, 512 threads, 4-pass reused reduce buffer
__global__ __launch_bounds__(512) void layer2_mfma(
        const u16* __restrict__ Y1bf, const float* __restrict__ scale1,
        const float* __restrict__ shift1, const u16* __restrict__ W2bf,
        const float* __restrict__ b2, float* __restrict__ gmax,
        float* __restrict__ gmin, float2* __restrict__ part) {
    __shared__ u16 Xs[128][72];
    __shared__ float sc1s[64], sh1s[64];
    __shared__ float red[32][128];
    int tid = threadIdx.x;
    long rowbase = (long)blockIdx.x * 128;
    if (tid < 64) { sc1s[tid] = scale1[tid]; sh1s[tid] = shift1[tid]; }
    __syncthreads();
    {   // X2 = relu(bn1(Y1)) -> bf16 tile; vectorized bf16 loads
        int r = tid >> 2, seg = (tid & 3) * 16;
        const u16* yp = &Y1bf[(rowbase + r) * 64 + seg];
        bf16x8 v0 = *(const bf16x8*)yp;
        bf16x8 v1 = *(const bf16x8*)(yp + 8);
#pragma unroll
        for (int j = 0; j < 8; ++j) {
            float x0 = fmaxf(sc1s[seg + j] * bf2f((u16)v0[j]) + sh1s[seg + j], 0.f);
            float x1 = fmaxf(sc1s[seg + 8 + j] * bf2f((u16)v1[j]) + sh1s[seg + 8 + j], 0.f);
            Xs[r][seg + j] = f2bf(x0);
            Xs[r][seg + 8 + j] = f2bf(x1);
        }
    }
    __syncthreads();
    int l = tid & 63, w = tid >> 6;
    int ar = l & 15, kg = l >> 4;
    bf16x8 a0 = *(const bf16x8*)&Xs[w * 16 + ar][kg * 8];
    bf16x8 a1 = *(const bf16x8*)&Xs[w * 16 + ar][32 + kg * 8];
    f32x4 acc[8];
#pragma unroll
    for (int t8 = 0; t8 < 8; ++t8) acc[t8] = (f32x4){0.f, 0.f, 0.f, 0.f};
#pragma unroll
    for (int t8 = 0; t8 < 8; ++t8) {
        const u16* wp = &W2bf[(t8 * 16 + ar) * 64 + kg * 8];
        bf16x8 bfr0 = *(const bf16x8*)wp;
        bf16x8 bfr1 = *(const bf16x8*)(wp + 32);
        acc[t8] = __builtin_amdgcn_mfma_f32_16x16x32_bf16(a0, bfr0, acc[t8], 0, 0, 0);
        acc[t8] = __builtin_amdgcn_mfma_f32_16x16x32_bf16(a1, bfr1, acc[t8], 0, 0, 0);
    }
    float ybias[8];
#pragma unroll
    for (int t8 = 0; t8 < 8; ++t8) ybias[t8] = b2[t8 * 16 + ar];
    // ---- pass 1: sum
#pragma unroll
    for (int t8 = 0; t8 < 8; ++t8) {
        float y0 = acc[t8][0] + ybias[t8], y1 = acc[t8][1] + ybias[t8];
        float y2 = acc[t8][2] + ybias[t8], y3 = acc[t8][3] + ybias[t8];
        red[w * 4 + kg][t8 * 16 + ar] = y0 + y1 + y2 + y3;
    }
    __syncthreads();
    float psum = 0.f;
    if (tid < 128) { for (int i = 0; i < 32; ++i) psum += red[i][tid]; }
    __syncthreads();
    // ---- pass 2: sumsq
#pragma unroll
    for (int t8 = 0; t8 < 8; ++t8) {
        float y0 = acc[t8][0] + ybias[t8], y1 = acc[t8][1] + ybias[t8];
        float y2 = acc[t8][2] + ybias[t8], y3 = acc[t8][3] + ybias[t8];
        red[w * 4 + kg][t8 * 16 + ar] = y0 * y0 + y1 * y1 + y2 * y2 + y3 * y3;
    }
    __syncthreads();
    if (tid < 128) {
        float psq = 0.f;
        for (int i = 0; i < 32; ++i) psq += red[i][tid];
        part[(size_t)blockIdx.x * 128 + tid] = make_float2(psum, psq);
    }
    __syncthreads();
    // ---- pass 3: max
#pragma unroll
    for (int t8 = 0; t8 < 8; ++t8) {
        float y0 = acc[t8][0] + ybias[t8], y1 = acc[t8][1] + ybias[t8];
        float y2 = acc[t8][2] + ybias[t8], y3 = acc[t8][3] + ybias[t8];
        red[w * 4 + kg][t8 * 16 + ar] = fmaxf(fmaxf(y0, y1), fmaxf(y2, y3));
    }
    __syncthreads();
    {
        int gsel = tid >> 7, col = tid & 127;     // 4 samples x 128 cols
        float mv = -3.0e38f;
        for (int rp = gsel * 8; rp < gsel * 8 + 8; ++rp) mv = fmaxf(mv, red[rp][col]);
        gmax[((size_t)blockIdx.x * 4 + gsel) * 128 + col] = mv;
    }
    __syncthreads();
    // ---- pass 4: min
#pragma unroll
    for (int t8 = 0; t8 < 8; ++t8) {
        float y0 = acc[t8][0] + ybias[t8], y1 = acc[t8][1] + ybias[t8];
        float y2 = acc[t8][2] + ybias[t8], y3 = acc[t8][3] + ybias[t8];
        red[w * 4 + kg][t8 * 16 + ar] = fminf(fminf(y0, y1), fminf(y2, y3));
    }
    __syncthreads();
    {
        int gsel = tid >> 7, col = tid & 127;
        float mv = 3.0e38f;
        for (int rp = gsel * 8; rp < gsel * 8 + 8; ++rp) mv = fminf(mv, red[rp][col]);
        gmin[((size_t)blockIdx.x * 4 + gsel) * 128 + col] = mv;
    }
}

// ---------------------------------------------------------------- final BN2 + relu + transpose
__global__ __launch_bounds__(256) void final_kernel(const float* __restrict__ gmax,
                                                    const float* __restrict__ gmin,
                                                    const float* __restrict__ scale2,
                                                    const float* __restrict__ shift2,
                                                    float* __restrict__ out1) {
    int b = blockIdx.x, st = blockIdx.y, ot = blockIdx.z;
    __shared__ float tile[32][33];
    int tid = threadIdx.x;
    for (int e = tid; e < 1024; e += 256) {
        int sl = e >> 5, ol = e & 31;
        int s = st * 32 + sl, o = ot * 32 + ol;
        size_t m = (size_t)b * 1024 + s;
        float sc = scale2[o];
        float v = (sc >= 0.f) ? gmax[m * 128 + o] : gmin[m * 128 + o];
        tile[sl][ol] = fmaxf(sc * v + shift2[o], 0.f);
    }
    __syncthreads();
    for (int e = tid; e < 1024; e += 256) {
        int ol = e >> 5, sl = e & 31;
        int s = st * 32 + sl, o = ot * 32 + ol;
        out1[(size_t)b * 131072 + (size_t)o * 1024 + s] = tile[sl][ol];
    }
}

// ---------------------------------------------------------------- launch
extern "C" void kernel_launch(void* const* d_in, const int* in_sizes, int n_in,
                              void* d_out, int out_size, void* d_ws, size_t ws_size,
                              hipStream_t stream) {
    const float* xyz   = (const float*)d_in[0];
    const float* pts   = (const float*)d_in[1];
    const float* W0    = (const float*)d_in[2];
    const float* b0    = (const float*)d_in[3];
    const float* g0    = (const float*)d_in[4];
    const float* beta0 = (const float*)d_in[5];
    const float* W1    = (const float*)d_in[6];
    const float* b1    = (const float*)d_in[7];
    const float* g1    = (const float*)d_in[8];
    const float* beta1 = (const float*)d_in[9];
    const float* W2    = (const float*)d_in[10];
    const float* b2    = (const float*)d_in[11];
    const float* g2    = (const float*)d_in[12];
    const float* beta2 = (const float*)d_in[13];

    float* out0 = (float*)d_out;                  // (B,3,1024)  = 49152
    float* out1 = (float*)d_out + 49152;          // (B,128,1024)

    char* w = (char*)d_ws;
    size_t off = 0;
    double4* xyzq = (double4*)(w + off);  off += (size_t)B_ * N_ * 32;   // 2 MB
    int*    idxbuf = (int*)(w + off);    off += (size_t)R_ * 4;
    float*  F      = (float*)(w + off);  off += (size_t)R_ * 6 * 4;
    u16*    Y1bf   = (u16*)(w + off);    off += (size_t)R_ * 64 * 2;
    float*  gmax   = (float*)(w + off);  off += (size_t)B_ * S_ * 128 * 4;
    float*  gmin   = (float*)(w + off);  off += (size_t)B_ * S_ * 128 * 4;
    float2* part   = (float2*)(w + off); off += (size_t)NB1_ * 128 * 2 * 4;
    float*  part0  = (float*)(w + off);  off += (size_t)4096 * 27 * 4;
    double* G27    = (double*)(w + off); off += 32 * 8;
    u16*    W1bf   = (u16*)(w + off);    off += 4096 * 2;
    u16*    W2bf   = (u16*)(w + off);    off += 8192 * 2;
    float*  ss     = (float*)(w + off);  off += 512 * 4;
    float* scale0 = ss,       *shift0 = ss + 64;
    float* scale1 = ss + 128, *shift1 = ss + 192;
    float* scale2 = ss + 256, *shift2 = ss + 384;

    prep_kernel<<<256, 256, 0, stream>>>(xyz, W1, W2, W1bf, W2bf, xyzq);
    fps_kernel<<<B_, 512, 0, stream>>>(xyz, out0);
    ballq_gather<<<(B_ * S_) / 4, 256, 0, stream>>>(xyzq, out0, xyz, pts, idxbuf, F, part0);
    reduce27<<<27, 256, 0, stream>>>(part0, G27);
    stats0_final<<<1, 64, 0, stream>>>(G27, W0, b0, g0, beta0, scale0, shift0);
    layer1_mfma<<<NB1_, 512, 0, stream>>>(F, W0, b0, scale0, shift0, W1bf, b1, Y1bf, part);
    reduce_stats<<<64, 256, 0, stream>>>(part, NB1_, 64, g1, beta1, scale1, shift1);
    layer2_mfma<<<NB1_, 512, 0, stream>>>(Y1bf, scale1, shift1, W2bf, b2, gmax, gmin, part);
    reduce_stats<<<128, 256, 0, stream>>>(part, NB1_, 128, g2, beta2, scale2, shift2);
    final_kernel<<<dim3(B_, 32, 4), 256, 0, stream>>>(gmax, gmin, scale2, shift2, out1);
}